// Round 22
// baseline (322.030 us; speedup 1.0000x reference)
//
#include <hip/hip_runtime.h>
#include <math.h>

// Problem constants
constexpr int BB  = 64;
constexpr int CIc = 3;
constexpr int HIc = 96, WIc = 96;
constexpr int Gc  = 8, HGc = 16, WGc = 16;
constexpr int HIDc = 18432;
constexpr int HIDLINc = 512;

using short8 = __attribute__((ext_vector_type(8))) short;
using s4     = __attribute__((ext_vector_type(4))) short;
using f32x16 = __attribute__((ext_vector_type(16))) float;

// bf16 split helpers. bfr = RNE (one-time weight packing only).
__device__ inline unsigned short bfr(float f) {
    unsigned int u = __float_as_uint(f);
    u = (u + 0x7FFFu + ((u >> 16) & 1u)) >> 16;
    return (unsigned short)u;
}
__device__ inline float ubf(unsigned short s) {
    return __uint_as_float(((unsigned int)s) << 16);
}
// Truncation 3-split (exact: v = h+m+l); ~3 VALU/level.
__device__ inline void tsplit(float v, unsigned short& H, unsigned short& M,
                              unsigned short& L) {
    unsigned int u = __float_as_uint(v);
    H = (unsigned short)(u >> 16);
    float r1 = v - __uint_as_float(u & 0xFFFF0000u);
    unsigned int u1 = __float_as_uint(r1);
    M = (unsigned short)(u1 >> 16);
    float r2 = r1 - __uint_as_float(u1 & 0xFFFF0000u);
    L = (unsigned short)(__float_as_uint(r2) >> 16);
}

// conv1b weight tables: [s=18][g=2][oc=32][j=8], k = s*16+g*8+j = tap*32+ci
__device__ __attribute__((aligned(16))) unsigned short g_wh[9216];
__device__ __attribute__((aligned(16))) unsigned short g_wm[9216];
__device__ __attribute__((aligned(16))) unsigned short g_wl[9216];

// conv1a weight tables: [s=3][g=2][oc=32][j=8], k = s*16+g*8+j = tap*4+ci
__device__ __attribute__((aligned(16))) unsigned short g_w1ah[1536];
__device__ __attribute__((aligned(16))) unsigned short g_w1am[1536];
__device__ __attribute__((aligned(16))) unsigned short g_w1al[1536];

// generic conv weight tables, per chunk [s][g][oc32][j], k = tap*CIN+ci
__device__ __attribute__((aligned(16))) unsigned short g_wph[276480];
__device__ __attribute__((aligned(16))) unsigned short g_wpm[276480];
__device__ __attribute__((aligned(16))) unsigned short g_wpl[276480];

__device__ inline void packN_one(const float* __restrict__ w, int CIN, int ofs,
                                 int idx)
{
    int chsz = 288 * CIN;
    int chunk = idx / chsz;
    int t = idx - chunk * chsz;
    int s = t >> 9;
    int rr = t & 511;
    int g = rr >> 8, oc32 = (rr >> 3) & 31, j = rr & 7;
    int nc16 = CIN / 16;
    int tap = s / nc16, c16 = s % nc16;
    int ci = c16 * 16 + g * 8 + j;
    int oc = chunk * 32 + oc32;
    float v = w[((size_t)oc * CIN + ci) * 9 + tap];
    unsigned short h = bfr(v);
    float r1 = v - ubf(h);
    unsigned short m = bfr(r1);
    g_wph[ofs + idx] = h; g_wpm[ofs + idx] = m; g_wpl[ofs + idx] = bfr(r1 - ubf(m));
}

__device__ inline void bz_one(unsigned short* __restrict__ Xh,
                              unsigned short* __restrict__ Xm,
                              unsigned short* __restrict__ Xl,
                              int PAD, int C, int idx)
{
    int RING = 4 * PAD - 4;
    int ci = idx % C;
    int cell = (idx / C) % RING;
    int b = idx / (C * RING);
    int y, x;
    if (cell < PAD)          { y = 0;       x = cell; }
    else if (cell < 2 * PAD) { y = PAD - 1; x = cell - PAD; }
    else { int t = cell - 2 * PAD; y = 1 + (t >> 1); x = (t & 1) ? PAD - 1 : 0; }
    size_t a = ((size_t)(b * PAD + y) * PAD + x) * C + ci;
    Xh[a] = 0; Xm[a] = 0; Xl[a] = 0;
}

// ---------------------------------------------------------------------------
// prep_all: one launch for weight packing + image split + border zeros.
// ---------------------------------------------------------------------------
__global__ void prep_all(const float* __restrict__ w1a, const float* __restrict__ w1b,
                         const float* __restrict__ w2a, const float* __restrict__ w2b,
                         const float* __restrict__ w3a, const float* __restrict__ w3b,
                         const float* __restrict__ image,
                         unsigned short* Ih, unsigned short* Im, unsigned short* Il,
                         unsigned short* X2h, unsigned short* X2m, unsigned short* X2l,
                         unsigned short* X3h, unsigned short* X3m, unsigned short* X3l,
                         unsigned short* X4h, unsigned short* X4m, unsigned short* X4l,
                         unsigned short* X5h, unsigned short* X5m, unsigned short* X5l)
{
    int idx = blockIdx.x * 256 + threadIdx.x;
    if (idx < 9216) {
        int j = idx & 7, oc = (idx >> 3) & 31, g = (idx >> 8) & 1, s = idx >> 9;
        int ci = 16 * (s & 1) + 8 * g + j;
        int tap = s >> 1;
        float v = w1b[(oc * 32 + ci) * 9 + tap];
        unsigned short h = bfr(v);
        float r1 = v - ubf(h);
        unsigned short m = bfr(r1);
        g_wh[idx] = h; g_wm[idx] = m; g_wl[idx] = bfr(r1 - ubf(m));
    } else if (idx < 27648) {
        packN_one(w2a, 32, 0, idx - 9216);
    } else if (idx < 64512) {
        packN_one(w2b, 64, 18432, idx - 27648);
    } else if (idx < 138240) {
        packN_one(w3a, 64, 55296, idx - 64512);
    } else if (idx < 285696) {
        packN_one(w3b, 128, 129024, idx - 138240);
    } else if (idx < 287232) {
        int i2 = idx - 285696;
        int j = i2 & 7, oc = (i2 >> 3) & 31, gg = (i2 >> 8) & 1, s = i2 >> 9;
        int k = s * 16 + gg * 8 + j;
        int tap = k >> 2, ci = k & 3;
        float v = (tap < 9 && ci < 3) ? w1a[((size_t)oc * 3 + ci) * 9 + tap] : 0.0f;
        unsigned short h = bfr(v);
        float r1 = v - ubf(h);
        unsigned short m = bfr(r1);
        g_w1ah[i2] = h; g_w1am[i2] = m; g_w1al[i2] = bfr(r1 - ubf(m));
    } else if (idx < 927232) {
        int c = idx - 287232;                 // img cell
        int x = c % 100;
        int t = c / 100;
        int y = t % 100;
        int b = t / 100;
        s4 H = {0, 0, 0, 0}, M = {0, 0, 0, 0}, L = {0, 0, 0, 0};
        if (y >= 2 && y < 98 && x >= 2 && x < 98) {
#pragma unroll
            for (int ci = 0; ci < 3; ++ci) {
                float v = image[((size_t)(b * 3 + ci) * 96 + (y - 2)) * 96 + (x - 2)];
                unsigned short hh, mm, ll;
                tsplit(v, hh, mm, ll);
                H[ci] = (short)hh; M[ci] = (short)mm; L[ci] = (short)ll;
            }
        }
        *(s4*)(Ih + (size_t)c * 4) = H;
        *(s4*)(Im + (size_t)c * 4) = M;
        *(s4*)(Il + (size_t)c * 4) = L;
    } else {
        int c = idx - 927232;
        if (c < 204800)        bz_one(X2h, X2m, X2l, 26, 32, c);
        else if (c < 614400)   bz_one(X3h, X3m, X3l, 26, 64, c - 204800);
        else if (c < 827392)   bz_one(X4h, X4m, X4l, 14, 64, c - 614400);
        else if (c < 1253376)  bz_one(X5h, X5m, X5l, 14, 128, c - 827392);
    }
}

// ---------------------------------------------------------------------------
// conv1ab v9: conv1a via MFMA + conv1b MFMA + fused 4x4 pool.
// LDS union: s_pool aliases s_hml (disjoint lifetimes -- pool writes begin
// only after the barrier ending all s_hml reads). LDS 29.2 -> 24.8 KB ->
// 6 blocks/CU (was 5): +20% resident waves against the ~32us idle fraction.
// ---------------------------------------------------------------------------
__global__ __launch_bounds__(256, 6)
void conv1ab(const unsigned short* __restrict__ Ih,
             const unsigned short* __restrict__ Im,
             const unsigned short* __restrict__ Il,
             const float* __restrict__ b1a, const float* __restrict__ b1b,
             unsigned short* __restrict__ X2h, unsigned short* __restrict__ X2m,
             unsigned short* __restrict__ X2l)
{
    // XCD swizzle: 4608 % 8 == 0, bijective
    const int id    = blockIdx.x;
    const int xcd   = id & 7;
    const int local = id >> 3;
    const int gblk  = xcd * 576 + local;
    const int b  = gblk / 72;
    const int r  = gblk % 72;
    const int yq = r / 3;      // 0..23 (pooled row)
    const int xt = r % 3;

    const int tid = threadIdx.x;
    const int wave = tid >> 6, lane = tid & 63;
    const int col = lane & 31, g = lane >> 5;

    __shared__ __align__(16) char s_mem[24480];        // s_hml / s_pool union
    short (*s_hml)[6][34][20] = (short(*)[6][34][20])s_mem;   // [3][6][34][20]
    float (*s_pool)[8][2][16] = (float(*)[8][2][16])s_mem;    // [4][8][2][16]
    __shared__ float s_b1a[32], s_b1b[32];
    if (tid < 32) { s_b1a[tid] = b1a[tid]; s_b1b[tid] = b1b[tid]; }
    __syncthreads();

    // ---- Phase A: conv1a via MFMA, 2 tiles per wave (tile 7 skipped) ----
    auto convA = [&](int tile, f32x16& acc) {
        int p = tile * 32 + col;
        int pc = p < 204 ? p : 203;
        int lr = pc / 34, lc = pc - (pc / 34) * 34;
        const size_t ibase =
            ((size_t)(b * 100 + 4 * yq + lr) * 100 + 32 * xt + lc) * 4;
#pragma unroll
        for (int s = 0; s < 3; ++s) {
            int tap0 = 4 * s + 2 * g; if (tap0 > 8) tap0 = 8;
            int tap1 = 4 * s + 2 * g + 1; if (tap1 > 8) tap1 = 8;
            int o0 = ((tap0 / 3) * 100 + tap0 % 3) * 4;
            int o1 = ((tap1 / 3) * 100 + tap1 % 3) * 4;
            s4 h0 = *(const s4*)(Ih + ibase + o0);
            s4 h1 = *(const s4*)(Ih + ibase + o1);
            s4 m0 = *(const s4*)(Im + ibase + o0);
            s4 m1 = *(const s4*)(Im + ibase + o1);
            s4 l0 = *(const s4*)(Il + ibase + o0);
            s4 l1 = *(const s4*)(Il + ibase + o1);
            short8 bh = __builtin_shufflevector(h0, h1, 0, 1, 2, 3, 4, 5, 6, 7);
            short8 bm = __builtin_shufflevector(m0, m1, 0, 1, 2, 3, 4, 5, 6, 7);
            short8 bl = __builtin_shufflevector(l0, l1, 0, 1, 2, 3, 4, 5, 6, 7);
            const int aidx = s * 512 + g * 256 + col * 8;
            short8 ah = *(const short8*)(g_w1ah + aidx);
            short8 am = *(const short8*)(g_w1am + aidx);
            short8 al = *(const short8*)(g_w1al + aidx);
            acc = __builtin_amdgcn_mfma_f32_32x32x16_bf16(ah, bh, acc, 0, 0, 0);
            acc = __builtin_amdgcn_mfma_f32_32x32x16_bf16(ah, bm, acc, 0, 0, 0);
            acc = __builtin_amdgcn_mfma_f32_32x32x16_bf16(am, bh, acc, 0, 0, 0);
            acc = __builtin_amdgcn_mfma_f32_32x32x16_bf16(am, bm, acc, 0, 0, 0);
            acc = __builtin_amdgcn_mfma_f32_32x32x16_bf16(al, bh, acc, 0, 0, 0);
            acc = __builtin_amdgcn_mfma_f32_32x32x16_bf16(ah, bl, acc, 0, 0, 0);
        }
    };

    f32x16 accA0 = {0,0,0,0,0,0,0,0,0,0,0,0,0,0,0,0};
    f32x16 accA1 = {0,0,0,0,0,0,0,0,0,0,0,0,0,0,0,0};
    convA(wave * 2, accA0);
    if (wave != 3) convA(wave * 2 + 1, accA1);

    // ---- conv1b: two halves; repack this half's oc from accA, then MFMA ----
    f32x16 acc0 = {0,0,0,0,0,0,0,0,0,0,0,0,0,0,0,0};
    f32x16 acc1 = {0,0,0,0,0,0,0,0,0,0,0,0,0,0,0,0};

#pragma unroll
    for (int half = 0; half < 2; ++half) {
        if (half) __syncthreads();          // MFMA(h0) done reading buffer

        // repack: write oc 16*half..+15 of both tiles into s_hml.
        // MASK: positions outside conv1a's 96x96 output domain must be 0.
#pragma unroll
        for (int t = 0; t < 2; ++t) {
            int tile = wave * 2 + t;
            int p = tile * 32 + col;
            if (tile < 7 && p < 204) {
                const f32x16& A = t ? accA1 : accA0;
                int lr = p / 34, lc = p - (p / 34) * 34;
                int gr = 4 * yq - 1 + lr, gc = 32 * xt - 1 + lc;
                bool valid = (gr >= 0 && gr < 96 && gc >= 0 && gc < 96);
                s4 H0, M0, L0, H1, M1, L1;
#pragma unroll
                for (int i = 0; i < 4; ++i) {
                    float v0 = valid ? fmaxf(A[8 * half + i] +
                                     s_b1a[16 * half + 4 * g + i], 0.0f) : 0.0f;
                    float v1 = valid ? fmaxf(A[8 * half + 4 + i] +
                                     s_b1a[16 * half + 8 + 4 * g + i], 0.0f) : 0.0f;
                    unsigned short hh, mm, ll;
                    tsplit(v0, hh, mm, ll);
                    H0[i] = (short)hh; M0[i] = (short)mm; L0[i] = (short)ll;
                    tsplit(v1, hh, mm, ll);
                    H1[i] = (short)hh; M1[i] = (short)mm; L1[i] = (short)ll;
                }
                *(s4*)&s_hml[0][lr][lc][4 * g]     = H0;
                *(s4*)&s_hml[0][lr][lc][8 + 4 * g] = H1;
                *(s4*)&s_hml[1][lr][lc][4 * g]     = M0;
                *(s4*)&s_hml[1][lr][lc][8 + 4 * g] = M1;
                *(s4*)&s_hml[2][lr][lc][4 * g]     = L0;
                *(s4*)&s_hml[2][lr][lc][8 + 4 * g] = L1;
            }
        }
        __syncthreads();

        // conv1b MFMA: 9 taps of this half (s = tap*2 + half)
        __builtin_amdgcn_s_setprio(1);
#pragma unroll
        for (int tap = 0; tap < 9; ++tap) {
            const int s = tap * 2 + half;
            const int dy = tap / 3, dx = tap % 3;
            const int aidx = s * 512 + g * 256 + col * 8;

            s4 a0 = *(const s4*)(&s_hml[0][wave + dy][col + dx][g * 8]);
            s4 a1 = *(const s4*)(&s_hml[0][wave + dy][col + dx][g * 8 + 4]);
            s4 b0 = *(const s4*)(&s_hml[1][wave + dy][col + dx][g * 8]);
            s4 b1 = *(const s4*)(&s_hml[1][wave + dy][col + dx][g * 8 + 4]);
            s4 c0 = *(const s4*)(&s_hml[2][wave + dy][col + dx][g * 8]);
            s4 c1 = *(const s4*)(&s_hml[2][wave + dy][col + dx][g * 8 + 4]);

            short8 bh = __builtin_shufflevector(a0, a1, 0, 1, 2, 3, 4, 5, 6, 7);
            short8 bm = __builtin_shufflevector(b0, b1, 0, 1, 2, 3, 4, 5, 6, 7);
            short8 bl = __builtin_shufflevector(c0, c1, 0, 1, 2, 3, 4, 5, 6, 7);

            short8 ah = *(const short8*)(g_wh + aidx);
            short8 am = *(const short8*)(g_wm + aidx);
            short8 al = *(const short8*)(g_wl + aidx);

            acc0 = __builtin_amdgcn_mfma_f32_32x32x16_bf16(ah, bh, acc0, 0, 0, 0);
            acc1 = __builtin_amdgcn_mfma_f32_32x32x16_bf16(ah, bm, acc1, 0, 0, 0);
            acc0 = __builtin_amdgcn_mfma_f32_32x32x16_bf16(am, bh, acc0, 0, 0, 0);
            acc1 = __builtin_amdgcn_mfma_f32_32x32x16_bf16(am, bm, acc1, 0, 0, 0);
            acc0 = __builtin_amdgcn_mfma_f32_32x32x16_bf16(al, bh, acc0, 0, 0, 0);
            acc1 = __builtin_amdgcn_mfma_f32_32x32x16_bf16(ah, bl, acc1, 0, 0, 0);
        }
        __builtin_amdgcn_s_setprio(0);
    }
    __syncthreads();        // all s_hml reads done; union region now s_pool

    // ---- bias + relu + in-wave col-pool (4 adjacent lanes) ----
#pragma unroll
    for (int rr = 0; rr < 16; ++rr) {
        int ocr = (rr & 3) + 8 * (rr >> 2) + 4 * g;
        float v = fmaxf(acc0[rr] + acc1[rr] + s_b1b[ocr], 0.0f);
        v = fmaxf(v, __shfl_xor(v, 1));
        v = fmaxf(v, __shfl_xor(v, 2));
        if ((col & 3) == 0) s_pool[wave][col >> 2][g][rr] = v;
    }
    __syncthreads();

    // ---- cross-wave row-pool + packed X2 write ----
    {
        int oc = tid & 31, pc = tid >> 5;       // 32 oc x 8 pooled cols
        if (pc < 8) {
            int gg = (oc >> 2) & 1;
            int rr = (oc & 3) + (((oc >> 3) & 3) << 2);
            float mv = s_pool[0][pc][gg][rr];
            mv = fmaxf(mv, s_pool[1][pc][gg][rr]);
            mv = fmaxf(mv, s_pool[2][pc][gg][rr]);
            mv = fmaxf(mv, s_pool[3][pc][gg][rr]);
            unsigned short h, m, l;
            tsplit(mv, h, m, l);
            size_t oa = ((size_t)(b * 26 + yq + 1) * 26 + xt * 8 + pc + 1) * 32 + oc;
            X2h[oa] = h; X2m[oa] = m; X2l[oa] = l;
        }
    }
}

// ---------------------------------------------------------------------------
// convN_mfma: generic implicit-GEMM conv, 1-WAVE BLOCKS (64 thr).
// OUTMODE 0: packed output; 1: fp32 NCHW + ReLU;
// OUTMODE 2 (HW=24 only): FUSED 2x2 maxpool -> packed [b][14][14][COUT].
// + XCD swizzle (grid % 8 == 0).
// ---------------------------------------------------------------------------
template<int CIN, int HW, int NCHUNK, int OUTMODE>
__global__ __launch_bounds__(64)
void convN_mfma(const unsigned short* __restrict__ Xh,
                const unsigned short* __restrict__ Xm,
                const unsigned short* __restrict__ Xl,
                int wofs, const float* __restrict__ bias,
                unsigned short* __restrict__ Yh,
                unsigned short* __restrict__ Ym,
                unsigned short* __restrict__ Yl,
                float* __restrict__ Yf)
{
    constexpr int PAD = HW + 2;
    constexpr int NC16 = CIN / 16;
    constexpr int CHSZ = 288 * CIN;
    constexpr int COUT = NCHUNK * 32;

    const int lane = threadIdx.x & 63;
    const int col = lane & 31, g = lane >> 5;
    const int cpx = gridDim.x >> 3;
    const int wid = (blockIdx.x & 7) * cpx + (blockIdx.x >> 3);

    const int chunk = wid % NCHUNK;
    const int wt = wid / NCHUNK;
    int b, y, x;
    if constexpr (OUTMODE == 2) {
        b = wt / 18;
        int trem = wt - b * 18;
        int ty = trem / 3, tx = trem - (trem / 3) * 3;
        y = ty * 4 + (col >> 3);
        x = tx * 8 + (col & 7);
    } else {
        const int P = wt * 32 + col;
        b = P / (HW * HW);
        int rem = P - b * (HW * HW);
        y = rem / HW; x = rem - y * HW;
    }

    const size_t ib = ((size_t)(b * PAD + y) * PAD + x) * CIN + g * 8;
    const int wbase = wofs + chunk * CHSZ;

    f32x16 acc0 = {0,0,0,0,0,0,0,0,0,0,0,0,0,0,0,0};
    f32x16 acc1 = {0,0,0,0,0,0,0,0,0,0,0,0,0,0,0,0};

#pragma unroll
    for (int tap = 0; tap < 9; ++tap) {
        const int dy = tap / 3, dx = tap % 3;
        for (int c16 = 0; c16 < NC16; ++c16) {
            const int s = tap * NC16 + c16;
            const int aidx = wbase + s * 512 + g * 256 + col * 8;
            const size_t xo = ib + (size_t)((dy * PAD + dx) * CIN + c16 * 16);
            short8 ah = *(const short8*)(g_wph + aidx);
            short8 am = *(const short8*)(g_wpm + aidx);
            short8 al = *(const short8*)(g_wpl + aidx);
            short8 bh = *(const short8*)(Xh + xo);
            short8 bm = *(const short8*)(Xm + xo);
            short8 bl = *(const short8*)(Xl + xo);
            acc0 = __builtin_amdgcn_mfma_f32_32x32x16_bf16(ah, bh, acc0, 0, 0, 0);
            acc1 = __builtin_amdgcn_mfma_f32_32x32x16_bf16(ah, bm, acc1, 0, 0, 0);
            acc0 = __builtin_amdgcn_mfma_f32_32x32x16_bf16(am, bh, acc0, 0, 0, 0);
            acc1 = __builtin_amdgcn_mfma_f32_32x32x16_bf16(am, bm, acc1, 0, 0, 0);
            acc0 = __builtin_amdgcn_mfma_f32_32x32x16_bf16(al, bh, acc0, 0, 0, 0);
            acc1 = __builtin_amdgcn_mfma_f32_32x32x16_bf16(ah, bl, acc1, 0, 0, 0);
        }
    }

    if constexpr (OUTMODE == 0) {
        const size_t obase =
            ((size_t)(b * PAD + y + 1) * PAD + (x + 1)) * COUT + chunk * 32;
#pragma unroll
        for (int q = 0; q < 4; ++q) {
            s4 H, M, L;
#pragma unroll
            for (int i = 0; i < 4; ++i) {
                int r = q * 4 + i;
                int ocr = i + 8 * q + 4 * g;
                float v = fmaxf(acc0[r] + acc1[r] + bias[chunk * 32 + ocr], 0.0f);
                unsigned short h, m, l;
                tsplit(v, h, m, l);
                H[i] = (short)h; M[i] = (short)m; L[i] = (short)l;
            }
            *(s4*)(Yh + obase + 8 * q + 4 * g) = H;
            *(s4*)(Ym + obase + 8 * q + 4 * g) = M;
            *(s4*)(Yl + obase + 8 * q + 4 * g) = L;
        }
    } else if constexpr (OUTMODE == 2) {
        float pv[16];
#pragma unroll
        for (int r = 0; r < 16; ++r) {
            int ocr = (r & 3) + 8 * (r >> 2) + 4 * g;
            float v = fmaxf(acc0[r] + acc1[r] + bias[chunk * 32 + ocr], 0.0f);
            v = fmaxf(v, __shfl_xor(v, 1));   // x-pair
            v = fmaxf(v, __shfl_xor(v, 8));   // y-pair
            pv[r] = v;
        }
        if ((lane & 9) == 0) {
            int py = y >> 1, px = x >> 1;
            const size_t obase =
                ((size_t)(b * 14 + py + 1) * 14 + (px + 1)) * COUT + chunk * 32;
#pragma unroll
            for (int q = 0; q < 4; ++q) {
                s4 H, M, L;
#pragma unroll
                for (int i = 0; i < 4; ++i) {
                    unsigned short h, m, l;
                    tsplit(pv[q * 4 + i], h, m, l);
                    H[i] = (short)h; M[i] = (short)m; L[i] = (short)l;
                }
                *(s4*)(Yh + obase + 8 * q + 4 * g) = H;
                *(s4*)(Ym + obase + 8 * q + 4 * g) = M;
                *(s4*)(Yl + obase + 8 * q + 4 * g) = L;
            }
        }
    } else {
#pragma unroll
        for (int r = 0; r < 16; ++r) {
            int ocr = chunk * 32 + (r & 3) + 8 * (r >> 2) + 4 * g;
            float v = fmaxf(acc0[r] + acc1[r] + bias[ocr], 0.0f);
            Yf[((size_t)(b * COUT + ocr) * HW + y) * HW + x] = v;
        }
    }
}

// ---------------------------------------------------------------------------
// lin1: (64, 18432) @ (18432, 512), split-K partials. Padded s_x[32][68].
// ---------------------------------------------------------------------------
constexpr int KSPLIT = 64;
__global__ __launch_bounds__(256)
void lin1_partial(const float* __restrict__ x, const float* __restrict__ w,
                  float* __restrict__ partial)
{
    const int j  = threadIdx.x % 64;
    const int bg = threadIdx.x / 64;
    const int jBase = blockIdx.x * 64;
    const int k  = blockIdx.y;
    const int i0 = k * 288;

    __shared__ float s_x[32][68];

    float acc[16];
#pragma unroll
    for (int u = 0; u < 16; ++u) acc[u] = 0.0f;

    for (int ib = 0; ib < 288; ib += 32) {
        __syncthreads();
        {
            int lb = threadIdx.x / 4;
            int lo = (threadIdx.x % 4) * 8;
            const float* src = x + (size_t)lb * HIDc + i0 + ib + lo;
            float4 a0 = *(const float4*)(src);
            float4 a1 = *(const float4*)(src + 4);
            float tmp[8] = {a0.x, a0.y, a0.z, a0.w, a1.x, a1.y, a1.z, a1.w};
#pragma unroll
            for (int r = 0; r < 8; ++r) s_x[lo + r][lb] = tmp[r];
        }
        __syncthreads();

        for (int ii = 0; ii < 32; ++ii) {
            float wv = w[(size_t)(i0 + ib + ii) * HIDLINc + jBase + j];
            const float4* xp = (const float4*)&s_x[ii][bg * 16];
            float4 x0 = xp[0], x1 = xp[1], x2 = xp[2], x3 = xp[3];
            acc[0]  = fmaf(x0.x, wv, acc[0]);
            acc[1]  = fmaf(x0.y, wv, acc[1]);
            acc[2]  = fmaf(x0.z, wv, acc[2]);
            acc[3]  = fmaf(x0.w, wv, acc[3]);
            acc[4]  = fmaf(x1.x, wv, acc[4]);
            acc[5]  = fmaf(x1.y, wv, acc[5]);
            acc[6]  = fmaf(x1.z, wv, acc[6]);
            acc[7]  = fmaf(x1.w, wv, acc[7]);
            acc[8]  = fmaf(x2.x, wv, acc[8]);
            acc[9]  = fmaf(x2.y, wv, acc[9]);
            acc[10] = fmaf(x2.z, wv, acc[10]);
            acc[11] = fmaf(x2.w, wv, acc[11]);
            acc[12] = fmaf(x3.x, wv, acc[12]);
            acc[13] = fmaf(x3.y, wv, acc[13]);
            acc[14] = fmaf(x3.z, wv, acc[14]);
            acc[15] = fmaf(x3.w, wv, acc[15]);
        }
    }

#pragma unroll
    for (int u = 0; u < 16; ++u) {
        int b = bg * 16 + u;
        partial[((size_t)k * 64 + b) * HIDLINc + jBase + j] = acc[u];
    }
}

__global__ void lin1_reduce(const float* __restrict__ partial,
                            const float* __restrict__ bias,
                            float* __restrict__ x1)
{
    int idx = blockIdx.x * blockDim.x + threadIdx.x;
    if (idx >= 64 * HIDLINc) return;
    int j = idx % HIDLINc;
    float s = 0.0f;
    for (int k = 0; k < KSPLIT; ++k)
        s += partial[(size_t)k * 64 * HIDLINc + idx];
    x1[idx] = fmaxf(s + bias[j], 0.0f);
}

__global__ __launch_bounds__(256)
void lin2_k(const float* __restrict__ x1, const float* __restrict__ w,
            const float* __restrict__ bias, float* __restrict__ x2)
{
    const int j  = threadIdx.x % 64;
    const int bl = threadIdx.x / 64;
    const int jBase = blockIdx.x * 64;
    const int b = blockIdx.y * 4 + bl;

    __shared__ float s_x[4][HIDLINc];
    for (int idx = threadIdx.x; idx < 4 * HIDLINc; idx += 256)
        s_x[idx / HIDLINc][idx % HIDLINc] =
            x1[(size_t)(blockIdx.y * 4 + idx / HIDLINc) * HIDLINc + idx % HIDLINc];
    __syncthreads();

    float acc = 0.0f;
    for (int i = 0; i < HIDLINc; ++i)
        acc = fmaf(s_x[bl][i], w[(size_t)i * HIDLINc + jBase + j], acc);
    x2[(size_t)b * HIDLINc + jBase + j] = fmaxf(acc + bias[jBase + j], 0.0f);
}

// ---------------------------------------------------------------------------
// lin3headpatch: FUSED lin3 + head + patch extraction. One block per batch.
// ---------------------------------------------------------------------------
__global__ __launch_bounds__(256)
void lin3headpatch_k(const float* __restrict__ x2, const float* __restrict__ w,
                     const float* __restrict__ bias, const float* __restrict__ noise,
                     const float* __restrict__ image,
                     float* __restrict__ outR, float* __restrict__ outMeans,
                     float* __restrict__ outSigmas)
{
    const int b = blockIdx.x;
    const int tid = threadIdx.x;
    __shared__ float s_x[HIDLINc];
    __shared__ float s_prep[24];
    __shared__ int s_pts[16];

    for (int i = tid; i < HIDLINc; i += 256)
        s_x[i] = x2[(size_t)b * HIDLINc + i];
    __syncthreads();

    if (tid < 24) {
        float acc = bias[tid];
        for (int i = 0; i < HIDLINc; ++i)
            acc = fmaf(s_x[i], w[i * 24 + tid], acc);
        s_prep[tid] = acc;
    }
    __syncthreads();

    if (tid < 8) {
        int id = b * Gc + tid;
        float m0 = s_prep[tid * 3 + 0];
        float m1 = s_prep[tid * 3 + 1];
        float sraw = s_prep[tid * 3 + 2];
        float s = sraw + 2.0f;
        float sig = fmaxf(s, 0.0f) + log1pf(expf(-fabsf(s)));
        sig += 1e-7f;
        float sg = sig * 95.0f;
        outMeans[id * 2 + 0] = m0;
        outMeans[id * 2 + 1] = m1;
        outSigmas[id * 2 + 0] = sg;
        outSigmas[id * 2 + 1] = sg;
        float sa0 = m0 + sg * noise[id * 2 + 0];
        float sa1 = m1 + sg * noise[id * 2 + 1];
        float t0 = 1.0f / (1.0f + expf(-sa0));
        float t1 = 1.0f / (1.0f + expf(-sa1));
        s_pts[tid * 2 + 0] = (int)rintf(t0 * 79.0f);
        s_pts[tid * 2 + 1] = (int)rintf(t1 * 79.0f);
    }
    __syncthreads();

    // patch copy: 8 groups x (3,16,16)
    constexpr int PSZ = CIc * HGc * WGc;      // 768
    for (int idx = tid; idx < Gc * PSZ; idx += 256) {
        int gq = idx / PSZ, rem = idx - gq * PSZ;
        int c = rem / (HGc * WGc), r2 = rem % (HGc * WGc);
        int hh = r2 / WGc, ww = r2 % WGc;
        int p0 = s_pts[gq * 2 + 0], p1 = s_pts[gq * 2 + 1];
        outR[(size_t)(b * Gc + gq) * PSZ + rem] =
            image[((size_t)(b * CIc + c) * HIc + p0 + hh) * WIc + p1 + ww];
    }
}

// ---------------------------------------------------------------------------
extern "C" void kernel_launch(void* const* d_in, const int* in_sizes, int n_in,
                              void* d_out, int out_size, void* d_ws, size_t ws_size,
                              hipStream_t stream)
{
    const float* image = (const float*)d_in[0];
    const float* noise = (const float*)d_in[1];
    const float* w1a = (const float*)d_in[2];
    const float* b1a = (const float*)d_in[3];
    const float* w1b = (const float*)d_in[4];
    const float* b1b = (const float*)d_in[5];
    const float* w2a = (const float*)d_in[6];
    const float* b2a = (const float*)d_in[7];
    const float* w2b = (const float*)d_in[8];
    const float* b2b = (const float*)d_in[9];
    const float* w3a = (const float*)d_in[10];
    const float* b3a = (const float*)d_in[11];
    const float* w3b = (const float*)d_in[12];
    const float* b3b = (const float*)d_in[13];
    const float* wl1 = (const float*)d_in[14];
    const float* bl1 = (const float*)d_in[15];
    const float* wl2 = (const float*)d_in[16];
    const float* bl2 = (const float*)d_in[17];
    const float* wl3 = (const float*)d_in[18];
    const float* bl3 = (const float*)d_in[19];

    float* out = (float*)d_out;
    float* ws  = (float*)d_ws;

    // Workspace (float offsets).
    unsigned short* X2h = (unsigned short*)(ws + 29884416);   // 28.5 MF
    unsigned short* X2m = (unsigned short*)(ws + 30670848);   // 29.25 MF
    unsigned short* X2l = (unsigned short*)(ws + 31457280);   // 30.0 MF
    unsigned short* X3h = (unsigned short*)(ws);
    unsigned short* X3m = (unsigned short*)(ws + 1572864);
    unsigned short* X3l = (unsigned short*)(ws + 3145728);
    unsigned short* X4h = (unsigned short*)(ws + 7340032);
    unsigned short* X4m = (unsigned short*)(ws + 7864320);
    unsigned short* X4l = (unsigned short*)(ws + 8388608);
    unsigned short* X5h = (unsigned short*)(ws + 8912896);
    unsigned short* X5m = (unsigned short*)(ws + 11010048);
    unsigned short* X5l = (unsigned short*)(ws + 12058624);
    float*  t5  = ws + 13107200;
    float*  part= ws + 14680064;
    float*  x1  = ws + 16777216;
    float*  x2  = x1 + 32768;
    unsigned short* Ih = (unsigned short*)(ws + 18874368);    // 18.0 MF
    unsigned short* Im = (unsigned short*)(ws + 20447232);    // 19.5 MF
    unsigned short* Il = (unsigned short*)(ws + 22020096);    // 21.0 MF

    // One preprocessing launch: weights + img split + border zeros
    prep_all<<<8518, 256, 0, stream>>>(w1a, w1b, w2a, w2b, w3a, w3b, image,
                                       Ih, Im, Il,
                                       X2h, X2m, X2l, X3h, X3m, X3l,
                                       X4h, X4m, X4l, X5h, X5m, X5l);

    // FUSED conv1a(MFMA) + conv1b(MFMA) + pool1 -> packed X2
    conv1ab<<<4608, 256, 0, stream>>>(Ih, Im, Il, b1a, b1b, X2h, X2m, X2l);

    // conv2a: X2 -> packed X3 (64 oc)
    convN_mfma<32, 24, 2, 0><<<2304, 64, 0, stream>>>(
        X2h, X2m, X2l, 0, b2a, X3h, X3m, X3l, nullptr);
    // conv2b + FUSED pool2: X3 -> packed X4 [b][14][14][64]
    convN_mfma<64, 24, 2, 2><<<2304, 64, 0, stream>>>(
        X3h, X3m, X3l, 18432, b2b, X4h, X4m, X4l, nullptr);
    // conv3a: X4 -> packed X5 (128 oc)
    convN_mfma<64, 12, 4, 0><<<1152, 64, 0, stream>>>(
        X4h, X4m, X4l, 55296, b3a, X5h, X5m, X5l, nullptr);
    // conv3b: X5 -> fp32 t5 = x (64,128,12,12)
    convN_mfma<128, 12, 4, 1><<<1152, 64, 0, stream>>>(
        X5h, X5m, X5l, 129024, b3b, nullptr, nullptr, nullptr, t5);

    // linear stack
    lin1_partial<<<dim3(8, KSPLIT), 256, 0, stream>>>(t5, wl1, part);
    lin1_reduce<<<(64 * HIDLINc + 255) / 256, 256, 0, stream>>>(part, bl1, x1);
    lin2_k<<<dim3(8, 16), 256, 0, stream>>>(x1, wl2, bl2, x2);
    // lin3 + head + patch fused
    lin3headpatch_k<<<64, 256, 0, stream>>>(
        x2, wl3, bl3, noise, image, out,
        out + (size_t)BB * Gc * CIc * HGc * WGc,
        out + (size_t)BB * Gc * CIc * HGc * WGc + BB * Gc * 2);
}

// Round 23
// 314.679 us; speedup vs baseline: 1.0234x; 1.0234x over previous
//
#include <hip/hip_runtime.h>
#include <math.h>

// Problem constants
constexpr int BB  = 64;
constexpr int CIc = 3;
constexpr int HIc = 96, WIc = 96;
constexpr int Gc  = 8, HGc = 16, WGc = 16;
constexpr int HIDc = 18432;
constexpr int HIDLINc = 512;

using short8 = __attribute__((ext_vector_type(8))) short;
using s4     = __attribute__((ext_vector_type(4))) short;
using f32x16 = __attribute__((ext_vector_type(16))) float;

// bf16 split helpers. bfr = RNE (one-time weight packing only).
__device__ inline unsigned short bfr(float f) {
    unsigned int u = __float_as_uint(f);
    u = (u + 0x7FFFu + ((u >> 16) & 1u)) >> 16;
    return (unsigned short)u;
}
__device__ inline float ubf(unsigned short s) {
    return __uint_as_float(((unsigned int)s) << 16);
}
// Truncation 3-split (exact: v = h+m+l); ~3 VALU/level.
__device__ inline void tsplit(float v, unsigned short& H, unsigned short& M,
                              unsigned short& L) {
    unsigned int u = __float_as_uint(v);
    H = (unsigned short)(u >> 16);
    float r1 = v - __uint_as_float(u & 0xFFFF0000u);
    unsigned int u1 = __float_as_uint(r1);
    M = (unsigned short)(u1 >> 16);
    float r2 = r1 - __uint_as_float(u1 & 0xFFFF0000u);
    L = (unsigned short)(__float_as_uint(r2) >> 16);
}

// conv1b weight tables: [s=18][g=2][oc=32][j=8], k = s*16+g*8+j = tap*32+ci
__device__ __attribute__((aligned(16))) unsigned short g_wh[9216];
__device__ __attribute__((aligned(16))) unsigned short g_wm[9216];
__device__ __attribute__((aligned(16))) unsigned short g_wl[9216];

// conv1a weight tables: [s=3][g=2][oc=32][j=8], k = s*16+g*8+j = tap*4+ci
__device__ __attribute__((aligned(16))) unsigned short g_w1ah[1536];
__device__ __attribute__((aligned(16))) unsigned short g_w1am[1536];
__device__ __attribute__((aligned(16))) unsigned short g_w1al[1536];

// generic conv weight tables, per chunk [s][g][oc32][j], k = tap*CIN+ci
__device__ __attribute__((aligned(16))) unsigned short g_wph[276480];
__device__ __attribute__((aligned(16))) unsigned short g_wpm[276480];
__device__ __attribute__((aligned(16))) unsigned short g_wpl[276480];

__device__ inline void packN_one(const float* __restrict__ w, int CIN, int ofs,
                                 int idx)
{
    int chsz = 288 * CIN;
    int chunk = idx / chsz;
    int t = idx - chunk * chsz;
    int s = t >> 9;
    int rr = t & 511;
    int g = rr >> 8, oc32 = (rr >> 3) & 31, j = rr & 7;
    int nc16 = CIN / 16;
    int tap = s / nc16, c16 = s % nc16;
    int ci = c16 * 16 + g * 8 + j;
    int oc = chunk * 32 + oc32;
    float v = w[((size_t)oc * CIN + ci) * 9 + tap];
    unsigned short h = bfr(v);
    float r1 = v - ubf(h);
    unsigned short m = bfr(r1);
    g_wph[ofs + idx] = h; g_wpm[ofs + idx] = m; g_wpl[ofs + idx] = bfr(r1 - ubf(m));
}

__device__ inline void bz_one(unsigned short* __restrict__ Xh,
                              unsigned short* __restrict__ Xm,
                              unsigned short* __restrict__ Xl,
                              int PAD, int C, int idx)
{
    int RING = 4 * PAD - 4;
    int ci = idx % C;
    int cell = (idx / C) % RING;
    int b = idx / (C * RING);
    int y, x;
    if (cell < PAD)          { y = 0;       x = cell; }
    else if (cell < 2 * PAD) { y = PAD - 1; x = cell - PAD; }
    else { int t = cell - 2 * PAD; y = 1 + (t >> 1); x = (t & 1) ? PAD - 1 : 0; }
    size_t a = ((size_t)(b * PAD + y) * PAD + x) * C + ci;
    Xh[a] = 0; Xm[a] = 0; Xl[a] = 0;
}

// ---------------------------------------------------------------------------
// prep_all: one launch for weight packing + image split + border zeros.
// ---------------------------------------------------------------------------
__global__ void prep_all(const float* __restrict__ w1a, const float* __restrict__ w1b,
                         const float* __restrict__ w2a, const float* __restrict__ w2b,
                         const float* __restrict__ w3a, const float* __restrict__ w3b,
                         const float* __restrict__ image,
                         unsigned short* Ih, unsigned short* Im, unsigned short* Il,
                         unsigned short* X2h, unsigned short* X2m, unsigned short* X2l,
                         unsigned short* X3h, unsigned short* X3m, unsigned short* X3l,
                         unsigned short* X4h, unsigned short* X4m, unsigned short* X4l,
                         unsigned short* X5h, unsigned short* X5m, unsigned short* X5l)
{
    int idx = blockIdx.x * 256 + threadIdx.x;
    if (idx < 9216) {
        int j = idx & 7, oc = (idx >> 3) & 31, g = (idx >> 8) & 1, s = idx >> 9;
        int ci = 16 * (s & 1) + 8 * g + j;
        int tap = s >> 1;
        float v = w1b[(oc * 32 + ci) * 9 + tap];
        unsigned short h = bfr(v);
        float r1 = v - ubf(h);
        unsigned short m = bfr(r1);
        g_wh[idx] = h; g_wm[idx] = m; g_wl[idx] = bfr(r1 - ubf(m));
    } else if (idx < 27648) {
        packN_one(w2a, 32, 0, idx - 9216);
    } else if (idx < 64512) {
        packN_one(w2b, 64, 18432, idx - 27648);
    } else if (idx < 138240) {
        packN_one(w3a, 64, 55296, idx - 64512);
    } else if (idx < 285696) {
        packN_one(w3b, 128, 129024, idx - 138240);
    } else if (idx < 287232) {
        int i2 = idx - 285696;
        int j = i2 & 7, oc = (i2 >> 3) & 31, gg = (i2 >> 8) & 1, s = i2 >> 9;
        int k = s * 16 + gg * 8 + j;
        int tap = k >> 2, ci = k & 3;
        float v = (tap < 9 && ci < 3) ? w1a[((size_t)oc * 3 + ci) * 9 + tap] : 0.0f;
        unsigned short h = bfr(v);
        float r1 = v - ubf(h);
        unsigned short m = bfr(r1);
        g_w1ah[i2] = h; g_w1am[i2] = m; g_w1al[i2] = bfr(r1 - ubf(m));
    } else if (idx < 927232) {
        int c = idx - 287232;                 // img cell
        int x = c % 100;
        int t = c / 100;
        int y = t % 100;
        int b = t / 100;
        s4 H = {0, 0, 0, 0}, M = {0, 0, 0, 0}, L = {0, 0, 0, 0};
        if (y >= 2 && y < 98 && x >= 2 && x < 98) {
#pragma unroll
            for (int ci = 0; ci < 3; ++ci) {
                float v = image[((size_t)(b * 3 + ci) * 96 + (y - 2)) * 96 + (x - 2)];
                unsigned short hh, mm, ll;
                tsplit(v, hh, mm, ll);
                H[ci] = (short)hh; M[ci] = (short)mm; L[ci] = (short)ll;
            }
        }
        *(s4*)(Ih + (size_t)c * 4) = H;
        *(s4*)(Im + (size_t)c * 4) = M;
        *(s4*)(Il + (size_t)c * 4) = L;
    } else {
        int c = idx - 927232;
        if (c < 204800)        bz_one(X2h, X2m, X2l, 26, 32, c);
        else if (c < 614400)   bz_one(X3h, X3m, X3l, 26, 64, c - 204800);
        else if (c < 827392)   bz_one(X4h, X4m, X4l, 14, 64, c - 614400);
        else if (c < 1253376)  bz_one(X5h, X5m, X5l, 14, 128, c - 827392);
    }
}

// ---------------------------------------------------------------------------
// conv1ab v10: conv1a via MFMA + conv1b MFMA + fused 4x4 pool.
// LDS union (25.1 KB -> 6 blocks/CU by LDS) + launch_bounds(256,5): the
// allocator targets 102 VGPR (no spill; r22's (256,6) forced 85 -> 92MB
// scratch spill). Actual residency = min(LDS 6, VGPR 10) = 6 blocks/CU.
// ---------------------------------------------------------------------------
__global__ __launch_bounds__(256, 5)
void conv1ab(const unsigned short* __restrict__ Ih,
             const unsigned short* __restrict__ Im,
             const unsigned short* __restrict__ Il,
             const float* __restrict__ b1a, const float* __restrict__ b1b,
             unsigned short* __restrict__ X2h, unsigned short* __restrict__ X2m,
             unsigned short* __restrict__ X2l)
{
    // XCD swizzle: 4608 % 8 == 0, bijective
    const int id    = blockIdx.x;
    const int xcd   = id & 7;
    const int local = id >> 3;
    const int gblk  = xcd * 576 + local;
    const int b  = gblk / 72;
    const int r  = gblk % 72;
    const int yq = r / 3;      // 0..23 (pooled row)
    const int xt = r % 3;

    const int tid = threadIdx.x;
    const int wave = tid >> 6, lane = tid & 63;
    const int col = lane & 31, g = lane >> 5;

    __shared__ __align__(16) char s_mem[24480];        // s_hml / s_pool union
    short (*s_hml)[6][34][20] = (short(*)[6][34][20])s_mem;   // [3][6][34][20]
    float (*s_pool)[8][2][16] = (float(*)[8][2][16])s_mem;    // [4][8][2][16]
    __shared__ float s_b1a[32], s_b1b[32];
    if (tid < 32) { s_b1a[tid] = b1a[tid]; s_b1b[tid] = b1b[tid]; }
    __syncthreads();

    // ---- Phase A: conv1a via MFMA, 2 tiles per wave (tile 7 skipped) ----
    auto convA = [&](int tile, f32x16& acc) {
        int p = tile * 32 + col;
        int pc = p < 204 ? p : 203;
        int lr = pc / 34, lc = pc - (pc / 34) * 34;
        const size_t ibase =
            ((size_t)(b * 100 + 4 * yq + lr) * 100 + 32 * xt + lc) * 4;
#pragma unroll
        for (int s = 0; s < 3; ++s) {
            int tap0 = 4 * s + 2 * g; if (tap0 > 8) tap0 = 8;
            int tap1 = 4 * s + 2 * g + 1; if (tap1 > 8) tap1 = 8;
            int o0 = ((tap0 / 3) * 100 + tap0 % 3) * 4;
            int o1 = ((tap1 / 3) * 100 + tap1 % 3) * 4;
            s4 h0 = *(const s4*)(Ih + ibase + o0);
            s4 h1 = *(const s4*)(Ih + ibase + o1);
            s4 m0 = *(const s4*)(Im + ibase + o0);
            s4 m1 = *(const s4*)(Im + ibase + o1);
            s4 l0 = *(const s4*)(Il + ibase + o0);
            s4 l1 = *(const s4*)(Il + ibase + o1);
            short8 bh = __builtin_shufflevector(h0, h1, 0, 1, 2, 3, 4, 5, 6, 7);
            short8 bm = __builtin_shufflevector(m0, m1, 0, 1, 2, 3, 4, 5, 6, 7);
            short8 bl = __builtin_shufflevector(l0, l1, 0, 1, 2, 3, 4, 5, 6, 7);
            const int aidx = s * 512 + g * 256 + col * 8;
            short8 ah = *(const short8*)(g_w1ah + aidx);
            short8 am = *(const short8*)(g_w1am + aidx);
            short8 al = *(const short8*)(g_w1al + aidx);
            acc = __builtin_amdgcn_mfma_f32_32x32x16_bf16(ah, bh, acc, 0, 0, 0);
            acc = __builtin_amdgcn_mfma_f32_32x32x16_bf16(ah, bm, acc, 0, 0, 0);
            acc = __builtin_amdgcn_mfma_f32_32x32x16_bf16(am, bh, acc, 0, 0, 0);
            acc = __builtin_amdgcn_mfma_f32_32x32x16_bf16(am, bm, acc, 0, 0, 0);
            acc = __builtin_amdgcn_mfma_f32_32x32x16_bf16(al, bh, acc, 0, 0, 0);
            acc = __builtin_amdgcn_mfma_f32_32x32x16_bf16(ah, bl, acc, 0, 0, 0);
        }
    };

    f32x16 accA0 = {0,0,0,0,0,0,0,0,0,0,0,0,0,0,0,0};
    f32x16 accA1 = {0,0,0,0,0,0,0,0,0,0,0,0,0,0,0,0};
    convA(wave * 2, accA0);
    if (wave != 3) convA(wave * 2 + 1, accA1);

    // ---- conv1b: two halves; repack this half's oc from accA, then MFMA ----
    f32x16 acc0 = {0,0,0,0,0,0,0,0,0,0,0,0,0,0,0,0};
    f32x16 acc1 = {0,0,0,0,0,0,0,0,0,0,0,0,0,0,0,0};

#pragma unroll
    for (int half = 0; half < 2; ++half) {
        if (half) __syncthreads();          // MFMA(h0) done reading buffer

        // repack: write oc 16*half..+15 of both tiles into s_hml.
        // MASK: positions outside conv1a's 96x96 output domain must be 0.
#pragma unroll
        for (int t = 0; t < 2; ++t) {
            int tile = wave * 2 + t;
            int p = tile * 32 + col;
            if (tile < 7 && p < 204) {
                const f32x16& A = t ? accA1 : accA0;
                int lr = p / 34, lc = p - (p / 34) * 34;
                int gr = 4 * yq - 1 + lr, gc = 32 * xt - 1 + lc;
                bool valid = (gr >= 0 && gr < 96 && gc >= 0 && gc < 96);
                s4 H0, M0, L0, H1, M1, L1;
#pragma unroll
                for (int i = 0; i < 4; ++i) {
                    float v0 = valid ? fmaxf(A[8 * half + i] +
                                     s_b1a[16 * half + 4 * g + i], 0.0f) : 0.0f;
                    float v1 = valid ? fmaxf(A[8 * half + 4 + i] +
                                     s_b1a[16 * half + 8 + 4 * g + i], 0.0f) : 0.0f;
                    unsigned short hh, mm, ll;
                    tsplit(v0, hh, mm, ll);
                    H0[i] = (short)hh; M0[i] = (short)mm; L0[i] = (short)ll;
                    tsplit(v1, hh, mm, ll);
                    H1[i] = (short)hh; M1[i] = (short)mm; L1[i] = (short)ll;
                }
                *(s4*)&s_hml[0][lr][lc][4 * g]     = H0;
                *(s4*)&s_hml[0][lr][lc][8 + 4 * g] = H1;
                *(s4*)&s_hml[1][lr][lc][4 * g]     = M0;
                *(s4*)&s_hml[1][lr][lc][8 + 4 * g] = M1;
                *(s4*)&s_hml[2][lr][lc][4 * g]     = L0;
                *(s4*)&s_hml[2][lr][lc][8 + 4 * g] = L1;
            }
        }
        __syncthreads();

        // conv1b MFMA: 9 taps of this half (s = tap*2 + half)
        __builtin_amdgcn_s_setprio(1);
#pragma unroll
        for (int tap = 0; tap < 9; ++tap) {
            const int s = tap * 2 + half;
            const int dy = tap / 3, dx = tap % 3;
            const int aidx = s * 512 + g * 256 + col * 8;

            s4 a0 = *(const s4*)(&s_hml[0][wave + dy][col + dx][g * 8]);
            s4 a1 = *(const s4*)(&s_hml[0][wave + dy][col + dx][g * 8 + 4]);
            s4 b0 = *(const s4*)(&s_hml[1][wave + dy][col + dx][g * 8]);
            s4 b1 = *(const s4*)(&s_hml[1][wave + dy][col + dx][g * 8 + 4]);
            s4 c0 = *(const s4*)(&s_hml[2][wave + dy][col + dx][g * 8]);
            s4 c1 = *(const s4*)(&s_hml[2][wave + dy][col + dx][g * 8 + 4]);

            short8 bh = __builtin_shufflevector(a0, a1, 0, 1, 2, 3, 4, 5, 6, 7);
            short8 bm = __builtin_shufflevector(b0, b1, 0, 1, 2, 3, 4, 5, 6, 7);
            short8 bl = __builtin_shufflevector(c0, c1, 0, 1, 2, 3, 4, 5, 6, 7);

            short8 ah = *(const short8*)(g_wh + aidx);
            short8 am = *(const short8*)(g_wm + aidx);
            short8 al = *(const short8*)(g_wl + aidx);

            acc0 = __builtin_amdgcn_mfma_f32_32x32x16_bf16(ah, bh, acc0, 0, 0, 0);
            acc1 = __builtin_amdgcn_mfma_f32_32x32x16_bf16(ah, bm, acc1, 0, 0, 0);
            acc0 = __builtin_amdgcn_mfma_f32_32x32x16_bf16(am, bh, acc0, 0, 0, 0);
            acc1 = __builtin_amdgcn_mfma_f32_32x32x16_bf16(am, bm, acc1, 0, 0, 0);
            acc0 = __builtin_amdgcn_mfma_f32_32x32x16_bf16(al, bh, acc0, 0, 0, 0);
            acc1 = __builtin_amdgcn_mfma_f32_32x32x16_bf16(ah, bl, acc1, 0, 0, 0);
        }
        __builtin_amdgcn_s_setprio(0);
    }
    __syncthreads();        // all s_hml reads done; union region now s_pool

    // ---- bias + relu + in-wave col-pool (4 adjacent lanes) ----
#pragma unroll
    for (int rr = 0; rr < 16; ++rr) {
        int ocr = (rr & 3) + 8 * (rr >> 2) + 4 * g;
        float v = fmaxf(acc0[rr] + acc1[rr] + s_b1b[ocr], 0.0f);
        v = fmaxf(v, __shfl_xor(v, 1));
        v = fmaxf(v, __shfl_xor(v, 2));
        if ((col & 3) == 0) s_pool[wave][col >> 2][g][rr] = v;
    }
    __syncthreads();

    // ---- cross-wave row-pool + packed X2 write ----
    {
        int oc = tid & 31, pc = tid >> 5;       // 32 oc x 8 pooled cols
        if (pc < 8) {
            int gg = (oc >> 2) & 1;
            int rr = (oc & 3) + (((oc >> 3) & 3) << 2);
            float mv = s_pool[0][pc][gg][rr];
            mv = fmaxf(mv, s_pool[1][pc][gg][rr]);
            mv = fmaxf(mv, s_pool[2][pc][gg][rr]);
            mv = fmaxf(mv, s_pool[3][pc][gg][rr]);
            unsigned short h, m, l;
            tsplit(mv, h, m, l);
            size_t oa = ((size_t)(b * 26 + yq + 1) * 26 + xt * 8 + pc + 1) * 32 + oc;
            X2h[oa] = h; X2m[oa] = m; X2l[oa] = l;
        }
    }
}

// ---------------------------------------------------------------------------
// convN_mfma: generic implicit-GEMM conv, 1-WAVE BLOCKS (64 thr).
// OUTMODE 0: packed output; 1: fp32 NCHW + ReLU;
// OUTMODE 2 (HW=24 only): FUSED 2x2 maxpool -> packed [b][14][14][COUT].
// + XCD swizzle (grid % 8 == 0).
// ---------------------------------------------------------------------------
template<int CIN, int HW, int NCHUNK, int OUTMODE>
__global__ __launch_bounds__(64)
void convN_mfma(const unsigned short* __restrict__ Xh,
                const unsigned short* __restrict__ Xm,
                const unsigned short* __restrict__ Xl,
                int wofs, const float* __restrict__ bias,
                unsigned short* __restrict__ Yh,
                unsigned short* __restrict__ Ym,
                unsigned short* __restrict__ Yl,
                float* __restrict__ Yf)
{
    constexpr int PAD = HW + 2;
    constexpr int NC16 = CIN / 16;
    constexpr int CHSZ = 288 * CIN;
    constexpr int COUT = NCHUNK * 32;

    const int lane = threadIdx.x & 63;
    const int col = lane & 31, g = lane >> 5;
    const int cpx = gridDim.x >> 3;
    const int wid = (blockIdx.x & 7) * cpx + (blockIdx.x >> 3);

    const int chunk = wid % NCHUNK;
    const int wt = wid / NCHUNK;
    int b, y, x;
    if constexpr (OUTMODE == 2) {
        b = wt / 18;
        int trem = wt - b * 18;
        int ty = trem / 3, tx = trem - (trem / 3) * 3;
        y = ty * 4 + (col >> 3);
        x = tx * 8 + (col & 7);
    } else {
        const int P = wt * 32 + col;
        b = P / (HW * HW);
        int rem = P - b * (HW * HW);
        y = rem / HW; x = rem - y * HW;
    }

    const size_t ib = ((size_t)(b * PAD + y) * PAD + x) * CIN + g * 8;
    const int wbase = wofs + chunk * CHSZ;

    f32x16 acc0 = {0,0,0,0,0,0,0,0,0,0,0,0,0,0,0,0};
    f32x16 acc1 = {0,0,0,0,0,0,0,0,0,0,0,0,0,0,0,0};

#pragma unroll
    for (int tap = 0; tap < 9; ++tap) {
        const int dy = tap / 3, dx = tap % 3;
        for (int c16 = 0; c16 < NC16; ++c16) {
            const int s = tap * NC16 + c16;
            const int aidx = wbase + s * 512 + g * 256 + col * 8;
            const size_t xo = ib + (size_t)((dy * PAD + dx) * CIN + c16 * 16);
            short8 ah = *(const short8*)(g_wph + aidx);
            short8 am = *(const short8*)(g_wpm + aidx);
            short8 al = *(const short8*)(g_wpl + aidx);
            short8 bh = *(const short8*)(Xh + xo);
            short8 bm = *(const short8*)(Xm + xo);
            short8 bl = *(const short8*)(Xl + xo);
            acc0 = __builtin_amdgcn_mfma_f32_32x32x16_bf16(ah, bh, acc0, 0, 0, 0);
            acc1 = __builtin_amdgcn_mfma_f32_32x32x16_bf16(ah, bm, acc1, 0, 0, 0);
            acc0 = __builtin_amdgcn_mfma_f32_32x32x16_bf16(am, bh, acc0, 0, 0, 0);
            acc1 = __builtin_amdgcn_mfma_f32_32x32x16_bf16(am, bm, acc1, 0, 0, 0);
            acc0 = __builtin_amdgcn_mfma_f32_32x32x16_bf16(al, bh, acc0, 0, 0, 0);
            acc1 = __builtin_amdgcn_mfma_f32_32x32x16_bf16(ah, bl, acc1, 0, 0, 0);
        }
    }

    if constexpr (OUTMODE == 0) {
        const size_t obase =
            ((size_t)(b * PAD + y + 1) * PAD + (x + 1)) * COUT + chunk * 32;
#pragma unroll
        for (int q = 0; q < 4; ++q) {
            s4 H, M, L;
#pragma unroll
            for (int i = 0; i < 4; ++i) {
                int r = q * 4 + i;
                int ocr = i + 8 * q + 4 * g;
                float v = fmaxf(acc0[r] + acc1[r] + bias[chunk * 32 + ocr], 0.0f);
                unsigned short h, m, l;
                tsplit(v, h, m, l);
                H[i] = (short)h; M[i] = (short)m; L[i] = (short)l;
            }
            *(s4*)(Yh + obase + 8 * q + 4 * g) = H;
            *(s4*)(Ym + obase + 8 * q + 4 * g) = M;
            *(s4*)(Yl + obase + 8 * q + 4 * g) = L;
        }
    } else if constexpr (OUTMODE == 2) {
        float pv[16];
#pragma unroll
        for (int r = 0; r < 16; ++r) {
            int ocr = (r & 3) + 8 * (r >> 2) + 4 * g;
            float v = fmaxf(acc0[r] + acc1[r] + bias[chunk * 32 + ocr], 0.0f);
            v = fmaxf(v, __shfl_xor(v, 1));   // x-pair
            v = fmaxf(v, __shfl_xor(v, 8));   // y-pair
            pv[r] = v;
        }
        if ((lane & 9) == 0) {
            int py = y >> 1, px = x >> 1;
            const size_t obase =
                ((size_t)(b * 14 + py + 1) * 14 + (px + 1)) * COUT + chunk * 32;
#pragma unroll
            for (int q = 0; q < 4; ++q) {
                s4 H, M, L;
#pragma unroll
                for (int i = 0; i < 4; ++i) {
                    unsigned short h, m, l;
                    tsplit(pv[q * 4 + i], h, m, l);
                    H[i] = (short)h; M[i] = (short)m; L[i] = (short)l;
                }
                *(s4*)(Yh + obase + 8 * q + 4 * g) = H;
                *(s4*)(Ym + obase + 8 * q + 4 * g) = M;
                *(s4*)(Yl + obase + 8 * q + 4 * g) = L;
            }
        }
    } else {
#pragma unroll
        for (int r = 0; r < 16; ++r) {
            int ocr = chunk * 32 + (r & 3) + 8 * (r >> 2) + 4 * g;
            float v = fmaxf(acc0[r] + acc1[r] + bias[ocr], 0.0f);
            Yf[((size_t)(b * COUT + ocr) * HW + y) * HW + x] = v;
        }
    }
}

// ---------------------------------------------------------------------------
// lin1: (64, 18432) @ (18432, 512), split-K partials. Padded s_x[32][68].
// ---------------------------------------------------------------------------
constexpr int KSPLIT = 64;
__global__ __launch_bounds__(256)
void lin1_partial(const float* __restrict__ x, const float* __restrict__ w,
                  float* __restrict__ partial)
{
    const int j  = threadIdx.x % 64;
    const int bg = threadIdx.x / 64;
    const int jBase = blockIdx.x * 64;
    const int k  = blockIdx.y;
    const int i0 = k * 288;

    __shared__ float s_x[32][68];

    float acc[16];
#pragma unroll
    for (int u = 0; u < 16; ++u) acc[u] = 0.0f;

    for (int ib = 0; ib < 288; ib += 32) {
        __syncthreads();
        {
            int lb = threadIdx.x / 4;
            int lo = (threadIdx.x % 4) * 8;
            const float* src = x + (size_t)lb * HIDc + i0 + ib + lo;
            float4 a0 = *(const float4*)(src);
            float4 a1 = *(const float4*)(src + 4);
            float tmp[8] = {a0.x, a0.y, a0.z, a0.w, a1.x, a1.y, a1.z, a1.w};
#pragma unroll
            for (int r = 0; r < 8; ++r) s_x[lo + r][lb] = tmp[r];
        }
        __syncthreads();

        for (int ii = 0; ii < 32; ++ii) {
            float wv = w[(size_t)(i0 + ib + ii) * HIDLINc + jBase + j];
            const float4* xp = (const float4*)&s_x[ii][bg * 16];
            float4 x0 = xp[0], x1 = xp[1], x2 = xp[2], x3 = xp[3];
            acc[0]  = fmaf(x0.x, wv, acc[0]);
            acc[1]  = fmaf(x0.y, wv, acc[1]);
            acc[2]  = fmaf(x0.z, wv, acc[2]);
            acc[3]  = fmaf(x0.w, wv, acc[3]);
            acc[4]  = fmaf(x1.x, wv, acc[4]);
            acc[5]  = fmaf(x1.y, wv, acc[5]);
            acc[6]  = fmaf(x1.z, wv, acc[6]);
            acc[7]  = fmaf(x1.w, wv, acc[7]);
            acc[8]  = fmaf(x2.x, wv, acc[8]);
            acc[9]  = fmaf(x2.y, wv, acc[9]);
            acc[10] = fmaf(x2.z, wv, acc[10]);
            acc[11] = fmaf(x2.w, wv, acc[11]);
            acc[12] = fmaf(x3.x, wv, acc[12]);
            acc[13] = fmaf(x3.y, wv, acc[13]);
            acc[14] = fmaf(x3.z, wv, acc[14]);
            acc[15] = fmaf(x3.w, wv, acc[15]);
        }
    }

#pragma unroll
    for (int u = 0; u < 16; ++u) {
        int b = bg * 16 + u;
        partial[((size_t)k * 64 + b) * HIDLINc + jBase + j] = acc[u];
    }
}

__global__ void lin1_reduce(const float* __restrict__ partial,
                            const float* __restrict__ bias,
                            float* __restrict__ x1)
{
    int idx = blockIdx.x * blockDim.x + threadIdx.x;
    if (idx >= 64 * HIDLINc) return;
    int j = idx % HIDLINc;
    float s = 0.0f;
    for (int k = 0; k < KSPLIT; ++k)
        s += partial[(size_t)k * 64 * HIDLINc + idx];
    x1[idx] = fmaxf(s + bias[j], 0.0f);
}

__global__ __launch_bounds__(256)
void lin2_k(const float* __restrict__ x1, const float* __restrict__ w,
            const float* __restrict__ bias, float* __restrict__ x2)
{
    const int j  = threadIdx.x % 64;
    const int bl = threadIdx.x / 64;
    const int jBase = blockIdx.x * 64;
    const int b = blockIdx.y * 4 + bl;

    __shared__ float s_x[4][HIDLINc];
    for (int idx = threadIdx.x; idx < 4 * HIDLINc; idx += 256)
        s_x[idx / HIDLINc][idx % HIDLINc] =
            x1[(size_t)(blockIdx.y * 4 + idx / HIDLINc) * HIDLINc + idx % HIDLINc];
    __syncthreads();

    float acc = 0.0f;
    for (int i = 0; i < HIDLINc; ++i)
        acc = fmaf(s_x[bl][i], w[(size_t)i * HIDLINc + jBase + j], acc);
    x2[(size_t)b * HIDLINc + jBase + j] = fmaxf(acc + bias[jBase + j], 0.0f);
}

// ---------------------------------------------------------------------------
// lin3headpatch: FUSED lin3 + head + patch extraction. One block per batch.
// ---------------------------------------------------------------------------
__global__ __launch_bounds__(256)
void lin3headpatch_k(const float* __restrict__ x2, const float* __restrict__ w,
                     const float* __restrict__ bias, const float* __restrict__ noise,
                     const float* __restrict__ image,
                     float* __restrict__ outR, float* __restrict__ outMeans,
                     float* __restrict__ outSigmas)
{
    const int b = blockIdx.x;
    const int tid = threadIdx.x;
    __shared__ float s_x[HIDLINc];
    __shared__ float s_prep[24];
    __shared__ int s_pts[16];

    for (int i = tid; i < HIDLINc; i += 256)
        s_x[i] = x2[(size_t)b * HIDLINc + i];
    __syncthreads();

    if (tid < 24) {
        float acc = bias[tid];
        for (int i = 0; i < HIDLINc; ++i)
            acc = fmaf(s_x[i], w[i * 24 + tid], acc);
        s_prep[tid] = acc;
    }
    __syncthreads();

    if (tid < 8) {
        int id = b * Gc + tid;
        float m0 = s_prep[tid * 3 + 0];
        float m1 = s_prep[tid * 3 + 1];
        float sraw = s_prep[tid * 3 + 2];
        float s = sraw + 2.0f;
        float sig = fmaxf(s, 0.0f) + log1pf(expf(-fabsf(s)));
        sig += 1e-7f;
        float sg = sig * 95.0f;
        outMeans[id * 2 + 0] = m0;
        outMeans[id * 2 + 1] = m1;
        outSigmas[id * 2 + 0] = sg;
        outSigmas[id * 2 + 1] = sg;
        float sa0 = m0 + sg * noise[id * 2 + 0];
        float sa1 = m1 + sg * noise[id * 2 + 1];
        float t0 = 1.0f / (1.0f + expf(-sa0));
        float t1 = 1.0f / (1.0f + expf(-sa1));
        s_pts[tid * 2 + 0] = (int)rintf(t0 * 79.0f);
        s_pts[tid * 2 + 1] = (int)rintf(t1 * 79.0f);
    }
    __syncthreads();

    // patch copy: 8 groups x (3,16,16)
    constexpr int PSZ = CIc * HGc * WGc;      // 768
    for (int idx = tid; idx < Gc * PSZ; idx += 256) {
        int gq = idx / PSZ, rem = idx - gq * PSZ;
        int c = rem / (HGc * WGc), r2 = rem % (HGc * WGc);
        int hh = r2 / WGc, ww = r2 % WGc;
        int p0 = s_pts[gq * 2 + 0], p1 = s_pts[gq * 2 + 1];
        outR[(size_t)(b * Gc + gq) * PSZ + rem] =
            image[((size_t)(b * CIc + c) * HIc + p0 + hh) * WIc + p1 + ww];
    }
}

// ---------------------------------------------------------------------------
extern "C" void kernel_launch(void* const* d_in, const int* in_sizes, int n_in,
                              void* d_out, int out_size, void* d_ws, size_t ws_size,
                              hipStream_t stream)
{
    const float* image = (const float*)d_in[0];
    const float* noise = (const float*)d_in[1];
    const float* w1a = (const float*)d_in[2];
    const float* b1a = (const float*)d_in[3];
    const float* w1b = (const float*)d_in[4];
    const float* b1b = (const float*)d_in[5];
    const float* w2a = (const float*)d_in[6];
    const float* b2a = (const float*)d_in[7];
    const float* w2b = (const float*)d_in[8];
    const float* b2b = (const float*)d_in[9];
    const float* w3a = (const float*)d_in[10];
    const float* b3a = (const float*)d_in[11];
    const float* w3b = (const float*)d_in[12];
    const float* b3b = (const float*)d_in[13];
    const float* wl1 = (const float*)d_in[14];
    const float* bl1 = (const float*)d_in[15];
    const float* wl2 = (const float*)d_in[16];
    const float* bl2 = (const float*)d_in[17];
    const float* wl3 = (const float*)d_in[18];
    const float* bl3 = (const float*)d_in[19];

    float* out = (float*)d_out;
    float* ws  = (float*)d_ws;

    // Workspace (float offsets).
    unsigned short* X2h = (unsigned short*)(ws + 29884416);   // 28.5 MF
    unsigned short* X2m = (unsigned short*)(ws + 30670848);   // 29.25 MF
    unsigned short* X2l = (unsigned short*)(ws + 31457280);   // 30.0 MF
    unsigned short* X3h = (unsigned short*)(ws);
    unsigned short* X3m = (unsigned short*)(ws + 1572864);
    unsigned short* X3l = (unsigned short*)(ws + 3145728);
    unsigned short* X4h = (unsigned short*)(ws + 7340032);
    unsigned short* X4m = (unsigned short*)(ws + 7864320);
    unsigned short* X4l = (unsigned short*)(ws + 8388608);
    unsigned short* X5h = (unsigned short*)(ws + 8912896);
    unsigned short* X5m = (unsigned short*)(ws + 11010048);
    unsigned short* X5l = (unsigned short*)(ws + 12058624);
    float*  t5  = ws + 13107200;
    float*  part= ws + 14680064;
    float*  x1  = ws + 16777216;
    float*  x2  = x1 + 32768;
    unsigned short* Ih = (unsigned short*)(ws + 18874368);    // 18.0 MF
    unsigned short* Im = (unsigned short*)(ws + 20447232);    // 19.5 MF
    unsigned short* Il = (unsigned short*)(ws + 22020096);    // 21.0 MF

    // One preprocessing launch: weights + img split + border zeros
    prep_all<<<8518, 256, 0, stream>>>(w1a, w1b, w2a, w2b, w3a, w3b, image,
                                       Ih, Im, Il,
                                       X2h, X2m, X2l, X3h, X3m, X3l,
                                       X4h, X4m, X4l, X5h, X5m, X5l);

    // FUSED conv1a(MFMA) + conv1b(MFMA) + pool1 -> packed X2
    conv1ab<<<4608, 256, 0, stream>>>(Ih, Im, Il, b1a, b1b, X2h, X2m, X2l);

    // conv2a: X2 -> packed X3 (64 oc)
    convN_mfma<32, 24, 2, 0><<<2304, 64, 0, stream>>>(
        X2h, X2m, X2l, 0, b2a, X3h, X3m, X3l, nullptr);
    // conv2b + FUSED pool2: X3 -> packed X4 [b][14][14][64]
    convN_mfma<64, 24, 2, 2><<<2304, 64, 0, stream>>>(
        X3h, X3m, X3l, 18432, b2b, X4h, X4m, X4l, nullptr);
    // conv3a: X4 -> packed X5 (128 oc)
    convN_mfma<64, 12, 4, 0><<<1152, 64, 0, stream>>>(
        X4h, X4m, X4l, 55296, b3a, X5h, X5m, X5l, nullptr);
    // conv3b: X5 -> fp32 t5 = x (64,128,12,12)
    convN_mfma<128, 12, 4, 1><<<1152, 64, 0, stream>>>(
        X5h, X5m, X5l, 129024, b3b, nullptr, nullptr, nullptr, t5);

    // linear stack
    lin1_partial<<<dim3(8, KSPLIT), 256, 0, stream>>>(t5, wl1, part);
    lin1_reduce<<<(64 * HIDLINc + 255) / 256, 256, 0, stream>>>(part, bl1, x1);
    lin2_k<<<dim3(8, 16), 256, 0, stream>>>(x1, wl2, bl2, x2);
    // lin3 + head + patch fused
    lin3headpatch_k<<<64, 256, 0, stream>>>(
        x2, wl3, bl3, noise, image, out,
        out + (size_t)BB * Gc * CIc * HGc * WGc,
        out + (size_t)BB * Gc * CIc * HGc * WGc + BB * Gc * 2);
}

// Round 24
// 311.007 us; speedup vs baseline: 1.0354x; 1.0118x over previous
//
#include <hip/hip_runtime.h>
#include <math.h>

// Problem constants
constexpr int BB  = 64;
constexpr int CIc = 3;
constexpr int HIc = 96, WIc = 96;
constexpr int Gc  = 8, HGc = 16, WGc = 16;
constexpr int HIDc = 18432;
constexpr int HIDLINc = 512;

using short8 = __attribute__((ext_vector_type(8))) short;
using s4     = __attribute__((ext_vector_type(4))) short;
using f32x16 = __attribute__((ext_vector_type(16))) float;

// bf16 split helpers. bfr = RNE (one-time weight packing only).
__device__ inline unsigned short bfr(float f) {
    unsigned int u = __float_as_uint(f);
    u = (u + 0x7FFFu + ((u >> 16) & 1u)) >> 16;
    return (unsigned short)u;
}
__device__ inline float ubf(unsigned short s) {
    return __uint_as_float(((unsigned int)s) << 16);
}
// Truncation 3-split (exact: v = h+m+l); ~3 VALU/level.
__device__ inline void tsplit(float v, unsigned short& H, unsigned short& M,
                              unsigned short& L) {
    unsigned int u = __float_as_uint(v);
    H = (unsigned short)(u >> 16);
    float r1 = v - __uint_as_float(u & 0xFFFF0000u);
    unsigned int u1 = __float_as_uint(r1);
    M = (unsigned short)(u1 >> 16);
    float r2 = r1 - __uint_as_float(u1 & 0xFFFF0000u);
    L = (unsigned short)(__float_as_uint(r2) >> 16);
}

// conv1b weight tables: [s=18][g=2][oc=32][j=8], k = s*16+g*8+j = tap*32+ci
__device__ __attribute__((aligned(16))) unsigned short g_wh[9216];
__device__ __attribute__((aligned(16))) unsigned short g_wm[9216];
__device__ __attribute__((aligned(16))) unsigned short g_wl[9216];

// conv1a weight tables: [s=3][g=2][oc=32][j=8], k = s*16+g*8+j = tap*4+ci
__device__ __attribute__((aligned(16))) unsigned short g_w1ah[1536];
__device__ __attribute__((aligned(16))) unsigned short g_w1am[1536];
__device__ __attribute__((aligned(16))) unsigned short g_w1al[1536];

// generic conv weight tables, per chunk [s][g][oc32][j], k = tap*CIN+ci
__device__ __attribute__((aligned(16))) unsigned short g_wph[276480];
__device__ __attribute__((aligned(16))) unsigned short g_wpm[276480];
__device__ __attribute__((aligned(16))) unsigned short g_wpl[276480];

__device__ inline void packN_one(const float* __restrict__ w, int CIN, int ofs,
                                 int idx)
{
    int chsz = 288 * CIN;
    int chunk = idx / chsz;
    int t = idx - chunk * chsz;
    int s = t >> 9;
    int rr = t & 511;
    int g = rr >> 8, oc32 = (rr >> 3) & 31, j = rr & 7;
    int nc16 = CIN / 16;
    int tap = s / nc16, c16 = s % nc16;
    int ci = c16 * 16 + g * 8 + j;
    int oc = chunk * 32 + oc32;
    float v = w[((size_t)oc * CIN + ci) * 9 + tap];
    unsigned short h = bfr(v);
    float r1 = v - ubf(h);
    unsigned short m = bfr(r1);
    g_wph[ofs + idx] = h; g_wpm[ofs + idx] = m; g_wpl[ofs + idx] = bfr(r1 - ubf(m));
}

__device__ inline void bz_one(unsigned short* __restrict__ Xh,
                              unsigned short* __restrict__ Xm,
                              unsigned short* __restrict__ Xl,
                              int PAD, int C, int idx)
{
    int RING = 4 * PAD - 4;
    int ci = idx % C;
    int cell = (idx / C) % RING;
    int b = idx / (C * RING);
    int y, x;
    if (cell < PAD)          { y = 0;       x = cell; }
    else if (cell < 2 * PAD) { y = PAD - 1; x = cell - PAD; }
    else { int t = cell - 2 * PAD; y = 1 + (t >> 1); x = (t & 1) ? PAD - 1 : 0; }
    size_t a = ((size_t)(b * PAD + y) * PAD + x) * C + ci;
    Xh[a] = 0; Xm[a] = 0; Xl[a] = 0;
}

// ---------------------------------------------------------------------------
// prep_all: one launch for weight packing + image split + border zeros.
// ---------------------------------------------------------------------------
__global__ void prep_all(const float* __restrict__ w1a, const float* __restrict__ w1b,
                         const float* __restrict__ w2a, const float* __restrict__ w2b,
                         const float* __restrict__ w3a, const float* __restrict__ w3b,
                         const float* __restrict__ image,
                         unsigned short* Ih, unsigned short* Im, unsigned short* Il,
                         unsigned short* X2h, unsigned short* X2m, unsigned short* X2l,
                         unsigned short* X3h, unsigned short* X3m, unsigned short* X3l,
                         unsigned short* X4h, unsigned short* X4m, unsigned short* X4l,
                         unsigned short* X5h, unsigned short* X5m, unsigned short* X5l)
{
    int idx = blockIdx.x * 256 + threadIdx.x;
    if (idx < 9216) {
        int j = idx & 7, oc = (idx >> 3) & 31, g = (idx >> 8) & 1, s = idx >> 9;
        int ci = 16 * (s & 1) + 8 * g + j;
        int tap = s >> 1;
        float v = w1b[(oc * 32 + ci) * 9 + tap];
        unsigned short h = bfr(v);
        float r1 = v - ubf(h);
        unsigned short m = bfr(r1);
        g_wh[idx] = h; g_wm[idx] = m; g_wl[idx] = bfr(r1 - ubf(m));
    } else if (idx < 27648) {
        packN_one(w2a, 32, 0, idx - 9216);
    } else if (idx < 64512) {
        packN_one(w2b, 64, 18432, idx - 27648);
    } else if (idx < 138240) {
        packN_one(w3a, 64, 55296, idx - 64512);
    } else if (idx < 285696) {
        packN_one(w3b, 128, 129024, idx - 138240);
    } else if (idx < 287232) {
        int i2 = idx - 285696;
        int j = i2 & 7, oc = (i2 >> 3) & 31, gg = (i2 >> 8) & 1, s = i2 >> 9;
        int k = s * 16 + gg * 8 + j;
        int tap = k >> 2, ci = k & 3;
        float v = (tap < 9 && ci < 3) ? w1a[((size_t)oc * 3 + ci) * 9 + tap] : 0.0f;
        unsigned short h = bfr(v);
        float r1 = v - ubf(h);
        unsigned short m = bfr(r1);
        g_w1ah[i2] = h; g_w1am[i2] = m; g_w1al[i2] = bfr(r1 - ubf(m));
    } else if (idx < 927232) {
        int c = idx - 287232;                 // img cell
        int x = c % 100;
        int t = c / 100;
        int y = t % 100;
        int b = t / 100;
        s4 H = {0, 0, 0, 0}, M = {0, 0, 0, 0}, L = {0, 0, 0, 0};
        if (y >= 2 && y < 98 && x >= 2 && x < 98) {
#pragma unroll
            for (int ci = 0; ci < 3; ++ci) {
                float v = image[((size_t)(b * 3 + ci) * 96 + (y - 2)) * 96 + (x - 2)];
                unsigned short hh, mm, ll;
                tsplit(v, hh, mm, ll);
                H[ci] = (short)hh; M[ci] = (short)mm; L[ci] = (short)ll;
            }
        }
        *(s4*)(Ih + (size_t)c * 4) = H;
        *(s4*)(Im + (size_t)c * 4) = M;
        *(s4*)(Il + (size_t)c * 4) = L;
    } else {
        int c = idx - 927232;
        if (c < 204800)        bz_one(X2h, X2m, X2l, 26, 32, c);
        else if (c < 614400)   bz_one(X3h, X3m, X3l, 26, 64, c - 204800);
        else if (c < 827392)   bz_one(X4h, X4m, X4l, 14, 64, c - 614400);
        else if (c < 1253376)  bz_one(X5h, X5m, X5l, 14, 128, c - 827392);
    }
}

// ---------------------------------------------------------------------------
// conv1ab v10: conv1a via MFMA + conv1b MFMA + fused 4x4 pool.
// (verified r23: no spill, ~93us structural floor at this phase layout)
// ---------------------------------------------------------------------------
__global__ __launch_bounds__(256, 5)
void conv1ab(const unsigned short* __restrict__ Ih,
             const unsigned short* __restrict__ Im,
             const unsigned short* __restrict__ Il,
             const float* __restrict__ b1a, const float* __restrict__ b1b,
             unsigned short* __restrict__ X2h, unsigned short* __restrict__ X2m,
             unsigned short* __restrict__ X2l)
{
    // XCD swizzle: 4608 % 8 == 0, bijective
    const int id    = blockIdx.x;
    const int xcd   = id & 7;
    const int local = id >> 3;
    const int gblk  = xcd * 576 + local;
    const int b  = gblk / 72;
    const int r  = gblk % 72;
    const int yq = r / 3;      // 0..23 (pooled row)
    const int xt = r % 3;

    const int tid = threadIdx.x;
    const int wave = tid >> 6, lane = tid & 63;
    const int col = lane & 31, g = lane >> 5;

    __shared__ __align__(16) char s_mem[24480];        // s_hml / s_pool union
    short (*s_hml)[6][34][20] = (short(*)[6][34][20])s_mem;   // [3][6][34][20]
    float (*s_pool)[8][2][16] = (float(*)[8][2][16])s_mem;    // [4][8][2][16]
    __shared__ float s_b1a[32], s_b1b[32];
    if (tid < 32) { s_b1a[tid] = b1a[tid]; s_b1b[tid] = b1b[tid]; }
    __syncthreads();

    // ---- Phase A: conv1a via MFMA, 2 tiles per wave (tile 7 skipped) ----
    auto convA = [&](int tile, f32x16& acc) {
        int p = tile * 32 + col;
        int pc = p < 204 ? p : 203;
        int lr = pc / 34, lc = pc - (pc / 34) * 34;
        const size_t ibase =
            ((size_t)(b * 100 + 4 * yq + lr) * 100 + 32 * xt + lc) * 4;
#pragma unroll
        for (int s = 0; s < 3; ++s) {
            int tap0 = 4 * s + 2 * g; if (tap0 > 8) tap0 = 8;
            int tap1 = 4 * s + 2 * g + 1; if (tap1 > 8) tap1 = 8;
            int o0 = ((tap0 / 3) * 100 + tap0 % 3) * 4;
            int o1 = ((tap1 / 3) * 100 + tap1 % 3) * 4;
            s4 h0 = *(const s4*)(Ih + ibase + o0);
            s4 h1 = *(const s4*)(Ih + ibase + o1);
            s4 m0 = *(const s4*)(Im + ibase + o0);
            s4 m1 = *(const s4*)(Im + ibase + o1);
            s4 l0 = *(const s4*)(Il + ibase + o0);
            s4 l1 = *(const s4*)(Il + ibase + o1);
            short8 bh = __builtin_shufflevector(h0, h1, 0, 1, 2, 3, 4, 5, 6, 7);
            short8 bm = __builtin_shufflevector(m0, m1, 0, 1, 2, 3, 4, 5, 6, 7);
            short8 bl = __builtin_shufflevector(l0, l1, 0, 1, 2, 3, 4, 5, 6, 7);
            const int aidx = s * 512 + g * 256 + col * 8;
            short8 ah = *(const short8*)(g_w1ah + aidx);
            short8 am = *(const short8*)(g_w1am + aidx);
            short8 al = *(const short8*)(g_w1al + aidx);
            acc = __builtin_amdgcn_mfma_f32_32x32x16_bf16(ah, bh, acc, 0, 0, 0);
            acc = __builtin_amdgcn_mfma_f32_32x32x16_bf16(ah, bm, acc, 0, 0, 0);
            acc = __builtin_amdgcn_mfma_f32_32x32x16_bf16(am, bh, acc, 0, 0, 0);
            acc = __builtin_amdgcn_mfma_f32_32x32x16_bf16(am, bm, acc, 0, 0, 0);
            acc = __builtin_amdgcn_mfma_f32_32x32x16_bf16(al, bh, acc, 0, 0, 0);
            acc = __builtin_amdgcn_mfma_f32_32x32x16_bf16(ah, bl, acc, 0, 0, 0);
        }
    };

    f32x16 accA0 = {0,0,0,0,0,0,0,0,0,0,0,0,0,0,0,0};
    f32x16 accA1 = {0,0,0,0,0,0,0,0,0,0,0,0,0,0,0,0};
    convA(wave * 2, accA0);
    if (wave != 3) convA(wave * 2 + 1, accA1);

    // ---- conv1b: two halves; repack this half's oc from accA, then MFMA ----
    f32x16 acc0 = {0,0,0,0,0,0,0,0,0,0,0,0,0,0,0,0};
    f32x16 acc1 = {0,0,0,0,0,0,0,0,0,0,0,0,0,0,0,0};

#pragma unroll
    for (int half = 0; half < 2; ++half) {
        if (half) __syncthreads();          // MFMA(h0) done reading buffer

        // repack: write oc 16*half..+15 of both tiles into s_hml.
        // MASK: positions outside conv1a's 96x96 output domain must be 0.
#pragma unroll
        for (int t = 0; t < 2; ++t) {
            int tile = wave * 2 + t;
            int p = tile * 32 + col;
            if (tile < 7 && p < 204) {
                const f32x16& A = t ? accA1 : accA0;
                int lr = p / 34, lc = p - (p / 34) * 34;
                int gr = 4 * yq - 1 + lr, gc = 32 * xt - 1 + lc;
                bool valid = (gr >= 0 && gr < 96 && gc >= 0 && gc < 96);
                s4 H0, M0, L0, H1, M1, L1;
#pragma unroll
                for (int i = 0; i < 4; ++i) {
                    float v0 = valid ? fmaxf(A[8 * half + i] +
                                     s_b1a[16 * half + 4 * g + i], 0.0f) : 0.0f;
                    float v1 = valid ? fmaxf(A[8 * half + 4 + i] +
                                     s_b1a[16 * half + 8 + 4 * g + i], 0.0f) : 0.0f;
                    unsigned short hh, mm, ll;
                    tsplit(v0, hh, mm, ll);
                    H0[i] = (short)hh; M0[i] = (short)mm; L0[i] = (short)ll;
                    tsplit(v1, hh, mm, ll);
                    H1[i] = (short)hh; M1[i] = (short)mm; L1[i] = (short)ll;
                }
                *(s4*)&s_hml[0][lr][lc][4 * g]     = H0;
                *(s4*)&s_hml[0][lr][lc][8 + 4 * g] = H1;
                *(s4*)&s_hml[1][lr][lc][4 * g]     = M0;
                *(s4*)&s_hml[1][lr][lc][8 + 4 * g] = M1;
                *(s4*)&s_hml[2][lr][lc][4 * g]     = L0;
                *(s4*)&s_hml[2][lr][lc][8 + 4 * g] = L1;
            }
        }
        __syncthreads();

        // conv1b MFMA: 9 taps of this half (s = tap*2 + half)
        __builtin_amdgcn_s_setprio(1);
#pragma unroll
        for (int tap = 0; tap < 9; ++tap) {
            const int s = tap * 2 + half;
            const int dy = tap / 3, dx = tap % 3;
            const int aidx = s * 512 + g * 256 + col * 8;

            s4 a0 = *(const s4*)(&s_hml[0][wave + dy][col + dx][g * 8]);
            s4 a1 = *(const s4*)(&s_hml[0][wave + dy][col + dx][g * 8 + 4]);
            s4 b0 = *(const s4*)(&s_hml[1][wave + dy][col + dx][g * 8]);
            s4 b1 = *(const s4*)(&s_hml[1][wave + dy][col + dx][g * 8 + 4]);
            s4 c0 = *(const s4*)(&s_hml[2][wave + dy][col + dx][g * 8]);
            s4 c1 = *(const s4*)(&s_hml[2][wave + dy][col + dx][g * 8 + 4]);

            short8 bh = __builtin_shufflevector(a0, a1, 0, 1, 2, 3, 4, 5, 6, 7);
            short8 bm = __builtin_shufflevector(b0, b1, 0, 1, 2, 3, 4, 5, 6, 7);
            short8 bl = __builtin_shufflevector(c0, c1, 0, 1, 2, 3, 4, 5, 6, 7);

            short8 ah = *(const short8*)(g_wh + aidx);
            short8 am = *(const short8*)(g_wm + aidx);
            short8 al = *(const short8*)(g_wl + aidx);

            acc0 = __builtin_amdgcn_mfma_f32_32x32x16_bf16(ah, bh, acc0, 0, 0, 0);
            acc1 = __builtin_amdgcn_mfma_f32_32x32x16_bf16(ah, bm, acc1, 0, 0, 0);
            acc0 = __builtin_amdgcn_mfma_f32_32x32x16_bf16(am, bh, acc0, 0, 0, 0);
            acc1 = __builtin_amdgcn_mfma_f32_32x32x16_bf16(am, bm, acc1, 0, 0, 0);
            acc0 = __builtin_amdgcn_mfma_f32_32x32x16_bf16(al, bh, acc0, 0, 0, 0);
            acc1 = __builtin_amdgcn_mfma_f32_32x32x16_bf16(ah, bl, acc1, 0, 0, 0);
        }
        __builtin_amdgcn_s_setprio(0);
    }
    __syncthreads();        // all s_hml reads done; union region now s_pool

    // ---- bias + relu + in-wave col-pool (4 adjacent lanes) ----
#pragma unroll
    for (int rr = 0; rr < 16; ++rr) {
        int ocr = (rr & 3) + 8 * (rr >> 2) + 4 * g;
        float v = fmaxf(acc0[rr] + acc1[rr] + s_b1b[ocr], 0.0f);
        v = fmaxf(v, __shfl_xor(v, 1));
        v = fmaxf(v, __shfl_xor(v, 2));
        if ((col & 3) == 0) s_pool[wave][col >> 2][g][rr] = v;
    }
    __syncthreads();

    // ---- cross-wave row-pool + packed X2 write ----
    {
        int oc = tid & 31, pc = tid >> 5;       // 32 oc x 8 pooled cols
        if (pc < 8) {
            int gg = (oc >> 2) & 1;
            int rr = (oc & 3) + (((oc >> 3) & 3) << 2);
            float mv = s_pool[0][pc][gg][rr];
            mv = fmaxf(mv, s_pool[1][pc][gg][rr]);
            mv = fmaxf(mv, s_pool[2][pc][gg][rr]);
            mv = fmaxf(mv, s_pool[3][pc][gg][rr]);
            unsigned short h, m, l;
            tsplit(mv, h, m, l);
            size_t oa = ((size_t)(b * 26 + yq + 1) * 26 + xt * 8 + pc + 1) * 32 + oc;
            X2h[oa] = h; X2m[oa] = m; X2l[oa] = l;
        }
    }
}

// ---------------------------------------------------------------------------
// convN_mfma: generic implicit-GEMM conv, 1-WAVE BLOCKS (64 thr).
// OUTMODE 0: packed output; 1: fp32 NCHW + ReLU;
// OUTMODE 2 (HW=24 only): FUSED 2x2 maxpool -> packed [b][14][14][COUT].
// + XCD swizzle (grid % 8 == 0).
// ---------------------------------------------------------------------------
template<int CIN, int HW, int NCHUNK, int OUTMODE>
__global__ __launch_bounds__(64)
void convN_mfma(const unsigned short* __restrict__ Xh,
                const unsigned short* __restrict__ Xm,
                const unsigned short* __restrict__ Xl,
                int wofs, const float* __restrict__ bias,
                unsigned short* __restrict__ Yh,
                unsigned short* __restrict__ Ym,
                unsigned short* __restrict__ Yl,
                float* __restrict__ Yf)
{
    constexpr int PAD = HW + 2;
    constexpr int NC16 = CIN / 16;
    constexpr int CHSZ = 288 * CIN;
    constexpr int COUT = NCHUNK * 32;

    const int lane = threadIdx.x & 63;
    const int col = lane & 31, g = lane >> 5;
    const int cpx = gridDim.x >> 3;
    const int wid = (blockIdx.x & 7) * cpx + (blockIdx.x >> 3);

    const int chunk = wid % NCHUNK;
    const int wt = wid / NCHUNK;
    int b, y, x;
    if constexpr (OUTMODE == 2) {
        b = wt / 18;
        int trem = wt - b * 18;
        int ty = trem / 3, tx = trem - (trem / 3) * 3;
        y = ty * 4 + (col >> 3);
        x = tx * 8 + (col & 7);
    } else {
        const int P = wt * 32 + col;
        b = P / (HW * HW);
        int rem = P - b * (HW * HW);
        y = rem / HW; x = rem - y * HW;
    }

    const size_t ib = ((size_t)(b * PAD + y) * PAD + x) * CIN + g * 8;
    const int wbase = wofs + chunk * CHSZ;

    f32x16 acc0 = {0,0,0,0,0,0,0,0,0,0,0,0,0,0,0,0};
    f32x16 acc1 = {0,0,0,0,0,0,0,0,0,0,0,0,0,0,0,0};

#pragma unroll
    for (int tap = 0; tap < 9; ++tap) {
        const int dy = tap / 3, dx = tap % 3;
        for (int c16 = 0; c16 < NC16; ++c16) {
            const int s = tap * NC16 + c16;
            const int aidx = wbase + s * 512 + g * 256 + col * 8;
            const size_t xo = ib + (size_t)((dy * PAD + dx) * CIN + c16 * 16);
            short8 ah = *(const short8*)(g_wph + aidx);
            short8 am = *(const short8*)(g_wpm + aidx);
            short8 al = *(const short8*)(g_wpl + aidx);
            short8 bh = *(const short8*)(Xh + xo);
            short8 bm = *(const short8*)(Xm + xo);
            short8 bl = *(const short8*)(Xl + xo);
            acc0 = __builtin_amdgcn_mfma_f32_32x32x16_bf16(ah, bh, acc0, 0, 0, 0);
            acc1 = __builtin_amdgcn_mfma_f32_32x32x16_bf16(ah, bm, acc1, 0, 0, 0);
            acc0 = __builtin_amdgcn_mfma_f32_32x32x16_bf16(am, bh, acc0, 0, 0, 0);
            acc1 = __builtin_amdgcn_mfma_f32_32x32x16_bf16(am, bm, acc1, 0, 0, 0);
            acc0 = __builtin_amdgcn_mfma_f32_32x32x16_bf16(al, bh, acc0, 0, 0, 0);
            acc1 = __builtin_amdgcn_mfma_f32_32x32x16_bf16(ah, bl, acc1, 0, 0, 0);
        }
    }

    if constexpr (OUTMODE == 0) {
        const size_t obase =
            ((size_t)(b * PAD + y + 1) * PAD + (x + 1)) * COUT + chunk * 32;
#pragma unroll
        for (int q = 0; q < 4; ++q) {
            s4 H, M, L;
#pragma unroll
            for (int i = 0; i < 4; ++i) {
                int r = q * 4 + i;
                int ocr = i + 8 * q + 4 * g;
                float v = fmaxf(acc0[r] + acc1[r] + bias[chunk * 32 + ocr], 0.0f);
                unsigned short h, m, l;
                tsplit(v, h, m, l);
                H[i] = (short)h; M[i] = (short)m; L[i] = (short)l;
            }
            *(s4*)(Yh + obase + 8 * q + 4 * g) = H;
            *(s4*)(Ym + obase + 8 * q + 4 * g) = M;
            *(s4*)(Yl + obase + 8 * q + 4 * g) = L;
        }
    } else if constexpr (OUTMODE == 2) {
        float pv[16];
#pragma unroll
        for (int r = 0; r < 16; ++r) {
            int ocr = (r & 3) + 8 * (r >> 2) + 4 * g;
            float v = fmaxf(acc0[r] + acc1[r] + bias[chunk * 32 + ocr], 0.0f);
            v = fmaxf(v, __shfl_xor(v, 1));   // x-pair
            v = fmaxf(v, __shfl_xor(v, 8));   // y-pair
            pv[r] = v;
        }
        if ((lane & 9) == 0) {
            int py = y >> 1, px = x >> 1;
            const size_t obase =
                ((size_t)(b * 14 + py + 1) * 14 + (px + 1)) * COUT + chunk * 32;
#pragma unroll
            for (int q = 0; q < 4; ++q) {
                s4 H, M, L;
#pragma unroll
                for (int i = 0; i < 4; ++i) {
                    unsigned short h, m, l;
                    tsplit(pv[q * 4 + i], h, m, l);
                    H[i] = (short)h; M[i] = (short)m; L[i] = (short)l;
                }
                *(s4*)(Yh + obase + 8 * q + 4 * g) = H;
                *(s4*)(Ym + obase + 8 * q + 4 * g) = M;
                *(s4*)(Yl + obase + 8 * q + 4 * g) = L;
            }
        }
    } else {
#pragma unroll
        for (int r = 0; r < 16; ++r) {
            int ocr = chunk * 32 + (r & 3) + 8 * (r >> 2) + 4 * g;
            float v = fmaxf(acc0[r] + acc1[r] + bias[ocr], 0.0f);
            Yf[((size_t)(b * COUT + ocr) * HW + y) * HW + x] = v;
        }
    }
}

// ---------------------------------------------------------------------------
// lin1: (64, 18432) @ (18432, 512), split-K partials.
// KSPLIT 64 -> 144 (grid 1152, ~4.5 blocks/CU vs 2: latency hiding) and
// full unroll of the ii loop (all 32 w-loads issue ahead of their FMAs).
// Padded s_x[32][68].
// ---------------------------------------------------------------------------
constexpr int KSPLIT = 144;             // 18432 / 144 = 128 per split
__global__ __launch_bounds__(256)
void lin1_partial(const float* __restrict__ x, const float* __restrict__ w,
                  float* __restrict__ partial)
{
    const int j  = threadIdx.x % 64;
    const int bg = threadIdx.x / 64;
    const int jBase = blockIdx.x * 64;
    const int k  = blockIdx.y;
    const int i0 = k * 128;

    __shared__ float s_x[32][68];

    float acc[16];
#pragma unroll
    for (int u = 0; u < 16; ++u) acc[u] = 0.0f;

    for (int ib = 0; ib < 128; ib += 32) {
        __syncthreads();
        {
            int lb = threadIdx.x / 4;
            int lo = (threadIdx.x % 4) * 8;
            const float* src = x + (size_t)lb * HIDc + i0 + ib + lo;
            float4 a0 = *(const float4*)(src);
            float4 a1 = *(const float4*)(src + 4);
            float tmp[8] = {a0.x, a0.y, a0.z, a0.w, a1.x, a1.y, a1.z, a1.w};
#pragma unroll
            for (int r = 0; r < 8; ++r) s_x[lo + r][lb] = tmp[r];
        }
        __syncthreads();

#pragma unroll
        for (int ii = 0; ii < 32; ++ii) {
            float wv = w[(size_t)(i0 + ib + ii) * HIDLINc + jBase + j];
            const float4* xp = (const float4*)&s_x[ii][bg * 16];
            float4 x0 = xp[0], x1 = xp[1], x2 = xp[2], x3 = xp[3];
            acc[0]  = fmaf(x0.x, wv, acc[0]);
            acc[1]  = fmaf(x0.y, wv, acc[1]);
            acc[2]  = fmaf(x0.z, wv, acc[2]);
            acc[3]  = fmaf(x0.w, wv, acc[3]);
            acc[4]  = fmaf(x1.x, wv, acc[4]);
            acc[5]  = fmaf(x1.y, wv, acc[5]);
            acc[6]  = fmaf(x1.z, wv, acc[6]);
            acc[7]  = fmaf(x1.w, wv, acc[7]);
            acc[8]  = fmaf(x2.x, wv, acc[8]);
            acc[9]  = fmaf(x2.y, wv, acc[9]);
            acc[10] = fmaf(x2.z, wv, acc[10]);
            acc[11] = fmaf(x2.w, wv, acc[11]);
            acc[12] = fmaf(x3.x, wv, acc[12]);
            acc[13] = fmaf(x3.y, wv, acc[13]);
            acc[14] = fmaf(x3.z, wv, acc[14]);
            acc[15] = fmaf(x3.w, wv, acc[15]);
        }
    }

#pragma unroll
    for (int u = 0; u < 16; ++u) {
        int b = bg * 16 + u;
        partial[((size_t)k * 64 + b) * HIDLINc + jBase + j] = acc[u];
    }
}

__global__ void lin1_reduce(const float* __restrict__ partial,
                            const float* __restrict__ bias,
                            float* __restrict__ x1)
{
    int idx = blockIdx.x * blockDim.x + threadIdx.x;
    if (idx >= 64 * HIDLINc) return;
    int j = idx % HIDLINc;
    float s = 0.0f;
    for (int k = 0; k < KSPLIT; ++k)
        s += partial[(size_t)k * 64 * HIDLINc + idx];
    x1[idx] = fmaxf(s + bias[j], 0.0f);
}

__global__ __launch_bounds__(256)
void lin2_k(const float* __restrict__ x1, const float* __restrict__ w,
            const float* __restrict__ bias, float* __restrict__ x2)
{
    const int j  = threadIdx.x % 64;
    const int bl = threadIdx.x / 64;
    const int jBase = blockIdx.x * 64;
    const int b = blockIdx.y * 4 + bl;

    __shared__ float s_x[4][HIDLINc];
    for (int idx = threadIdx.x; idx < 4 * HIDLINc; idx += 256)
        s_x[idx / HIDLINc][idx % HIDLINc] =
            x1[(size_t)(blockIdx.y * 4 + idx / HIDLINc) * HIDLINc + idx % HIDLINc];
    __syncthreads();

    float acc = 0.0f;
    for (int i = 0; i < HIDLINc; ++i)
        acc = fmaf(s_x[bl][i], w[(size_t)i * HIDLINc + jBase + j], acc);
    x2[(size_t)b * HIDLINc + jBase + j] = fmaxf(acc + bias[jBase + j], 0.0f);
}

// ---------------------------------------------------------------------------
// lin3headpatch: FUSED lin3 + head + patch extraction. One block per batch.
// ---------------------------------------------------------------------------
__global__ __launch_bounds__(256)
void lin3headpatch_k(const float* __restrict__ x2, const float* __restrict__ w,
                     const float* __restrict__ bias, const float* __restrict__ noise,
                     const float* __restrict__ image,
                     float* __restrict__ outR, float* __restrict__ outMeans,
                     float* __restrict__ outSigmas)
{
    const int b = blockIdx.x;
    const int tid = threadIdx.x;
    __shared__ float s_x[HIDLINc];
    __shared__ float s_prep[24];
    __shared__ int s_pts[16];

    for (int i = tid; i < HIDLINc; i += 256)
        s_x[i] = x2[(size_t)b * HIDLINc + i];
    __syncthreads();

    if (tid < 24) {
        float acc = bias[tid];
        for (int i = 0; i < HIDLINc; ++i)
            acc = fmaf(s_x[i], w[i * 24 + tid], acc);
        s_prep[tid] = acc;
    }
    __syncthreads();

    if (tid < 8) {
        int id = b * Gc + tid;
        float m0 = s_prep[tid * 3 + 0];
        float m1 = s_prep[tid * 3 + 1];
        float sraw = s_prep[tid * 3 + 2];
        float s = sraw + 2.0f;
        float sig = fmaxf(s, 0.0f) + log1pf(expf(-fabsf(s)));
        sig += 1e-7f;
        float sg = sig * 95.0f;
        outMeans[id * 2 + 0] = m0;
        outMeans[id * 2 + 1] = m1;
        outSigmas[id * 2 + 0] = sg;
        outSigmas[id * 2 + 1] = sg;
        float sa0 = m0 + sg * noise[id * 2 + 0];
        float sa1 = m1 + sg * noise[id * 2 + 1];
        float t0 = 1.0f / (1.0f + expf(-sa0));
        float t1 = 1.0f / (1.0f + expf(-sa1));
        s_pts[tid * 2 + 0] = (int)rintf(t0 * 79.0f);
        s_pts[tid * 2 + 1] = (int)rintf(t1 * 79.0f);
    }
    __syncthreads();

    // patch copy: 8 groups x (3,16,16)
    constexpr int PSZ = CIc * HGc * WGc;      // 768
    for (int idx = tid; idx < Gc * PSZ; idx += 256) {
        int gq = idx / PSZ, rem = idx - gq * PSZ;
        int c = rem / (HGc * WGc), r2 = rem % (HGc * WGc);
        int hh = r2 / WGc, ww = r2 % WGc;
        int p0 = s_pts[gq * 2 + 0], p1 = s_pts[gq * 2 + 1];
        outR[(size_t)(b * Gc + gq) * PSZ + rem] =
            image[((size_t)(b * CIc + c) * HIc + p0 + hh) * WIc + p1 + ww];
    }
}

// ---------------------------------------------------------------------------
extern "C" void kernel_launch(void* const* d_in, const int* in_sizes, int n_in,
                              void* d_out, int out_size, void* d_ws, size_t ws_size,
                              hipStream_t stream)
{
    const float* image = (const float*)d_in[0];
    const float* noise = (const float*)d_in[1];
    const float* w1a = (const float*)d_in[2];
    const float* b1a = (const float*)d_in[3];
    const float* w1b = (const float*)d_in[4];
    const float* b1b = (const float*)d_in[5];
    const float* w2a = (const float*)d_in[6];
    const float* b2a = (const float*)d_in[7];
    const float* w2b = (const float*)d_in[8];
    const float* b2b = (const float*)d_in[9];
    const float* w3a = (const float*)d_in[10];
    const float* b3a = (const float*)d_in[11];
    const float* w3b = (const float*)d_in[12];
    const float* b3b = (const float*)d_in[13];
    const float* wl1 = (const float*)d_in[14];
    const float* bl1 = (const float*)d_in[15];
    const float* wl2 = (const float*)d_in[16];
    const float* bl2 = (const float*)d_in[17];
    const float* wl3 = (const float*)d_in[18];
    const float* bl3 = (const float*)d_in[19];

    float* out = (float*)d_out;
    float* ws  = (float*)d_ws;

    // Workspace (float offsets).
    unsigned short* X2h = (unsigned short*)(ws + 29884416);   // 28.5 MF
    unsigned short* X2m = (unsigned short*)(ws + 30670848);   // 29.25 MF
    unsigned short* X2l = (unsigned short*)(ws + 31457280);   // 30.0 MF
    unsigned short* X3h = (unsigned short*)(ws);
    unsigned short* X3m = (unsigned short*)(ws + 1572864);
    unsigned short* X3l = (unsigned short*)(ws + 3145728);
    unsigned short* X4h = (unsigned short*)(ws + 7340032);
    unsigned short* X4m = (unsigned short*)(ws + 7864320);
    unsigned short* X4l = (unsigned short*)(ws + 8388608);
    unsigned short* X5h = (unsigned short*)(ws + 8912896);
    unsigned short* X5m = (unsigned short*)(ws + 11010048);
    unsigned short* X5l = (unsigned short*)(ws + 12058624);
    float*  t5  = ws + 13107200;
    float*  x1  = ws + 16777216;
    float*  x2  = x1 + 32768;
    unsigned short* Ih = (unsigned short*)(ws + 18874368);    // 18.0 MF
    unsigned short* Im = (unsigned short*)(ws + 20447232);    // 19.5 MF
    unsigned short* Il = (unsigned short*)(ws + 22020096);    // 21.0 MF
    // lin1 partials (144*64*512 = 4,718,592 floats) reuse the dead I region
    // (Ih/Im/Il are consumed by conv1ab, dead before lin1): exact fit.
    float*  part= ws + 18874368;

    // One preprocessing launch: weights + img split + border zeros
    prep_all<<<8518, 256, 0, stream>>>(w1a, w1b, w2a, w2b, w3a, w3b, image,
                                       Ih, Im, Il,
                                       X2h, X2m, X2l, X3h, X3m, X3l,
                                       X4h, X4m, X4l, X5h, X5m, X5l);

    // FUSED conv1a(MFMA) + conv1b(MFMA) + pool1 -> packed X2
    conv1ab<<<4608, 256, 0, stream>>>(Ih, Im, Il, b1a, b1b, X2h, X2m, X2l);

    // conv2a: X2 -> packed X3 (64 oc)
    convN_mfma<32, 24, 2, 0><<<2304, 64, 0, stream>>>(
        X2h, X2m, X2l, 0, b2a, X3h, X3m, X3l, nullptr);
    // conv2b + FUSED pool2: X3 -> packed X4 [b][14][14][64]
    convN_mfma<64, 24, 2, 2><<<2304, 64, 0, stream>>>(
        X3h, X3m, X3l, 18432, b2b, X4h, X4m, X4l, nullptr);
    // conv3a: X4 -> packed X5 (128 oc)
    convN_mfma<64, 12, 4, 0><<<1152, 64, 0, stream>>>(
        X4h, X4m, X4l, 55296, b3a, X5h, X5m, X5l, nullptr);
    // conv3b: X5 -> fp32 t5 = x (64,128,12,12)
    convN_mfma<128, 12, 4, 1><<<1152, 64, 0, stream>>>(
        X5h, X5m, X5l, 129024, b3b, nullptr, nullptr, nullptr, t5);

    // linear stack
    lin1_partial<<<dim3(8, KSPLIT), 256, 0, stream>>>(t5, wl1, part);
    lin1_reduce<<<(64 * HIDLINc + 255) / 256, 256, 0, stream>>>(part, bl1, x1);
    lin2_k<<<dim3(8, 16), 256, 0, stream>>>(x1, wl2, bl2, x2);
    // lin3 + head + patch fused
    lin3headpatch_k<<<64, 256, 0, stream>>>(
        x2, wl3, bl3, noise, image, out,
        out + (size_t)BB * Gc * CIc * HGc * WGc,
        out + (size_t)BB * Gc * CIc * HGc * WGc + BB * Gc * 2);
}